// Round 8
// baseline (84.780 us; speedup 1.0000x reference)
//
#include <hip/hip_runtime.h>

// ---------------------------------------------------------------------------
// SlidingWindowAttention on MI355X (gfx950)
// B=2 T=2048 C=1024 H=16 D=64 WINDOW=256
// GEMMs: 32x32x16 f16 MFMA (4060 FLOP/cyc vs 3378 for 16x16x32), 128-tile,
//        BK=64, 2-barrier m97-class core, (row&7)<<4 XOR-swizzled LDS.
// attn: 16x16x32 MFMA flash-style, QBLK=128, KVBLK=64.
// ---------------------------------------------------------------------------

typedef _Float16 f16;
typedef _Float16 half8 __attribute__((ext_vector_type(8)));
typedef _Float16 half4 __attribute__((ext_vector_type(4)));
typedef float    f32x4 __attribute__((ext_vector_type(4)));
typedef float    f32x16 __attribute__((ext_vector_type(16)));

#define MFMA16(a, b, c) __builtin_amdgcn_mfma_f32_16x16x32_f16((a), (b), (c), 0, 0, 0)
#define MFMA32(a, b, c) __builtin_amdgcn_mfma_f32_32x32x16_f16((a), (b), (c), 0, 0, 0)

__device__ __forceinline__ void gload16(const void* g, void* l) {
  __builtin_amdgcn_global_load_lds(
      (const __attribute__((address_space(1))) void*)g,
      (__attribute__((address_space(3))) void*)l, 16, 0, 0);
}

// ---------------------------------------------------------------------------
// prep: blocks 0..2047 convert x f32->f16; blocks 2048..6143 transpose weights
__global__ __launch_bounds__(256) void prep_kernel(
    const float* __restrict__ x, f16* __restrict__ xb,
    const float* __restrict__ W0, const float* __restrict__ W1,
    const float* __restrict__ W2, const float* __restrict__ W3,
    f16* __restrict__ T0, f16* __restrict__ T1,
    f16* __restrict__ T2, f16* __restrict__ T3) {
  const int bid = blockIdx.x;
  if (bid < 2048) {
    const int idx = (bid * 256 + threadIdx.x) * 8;
    const float4 a = *(const float4*)(x + idx);
    const float4 b = *(const float4*)(x + idx + 4);
    half8 h;
    h[0] = (f16)a.x; h[1] = (f16)a.y; h[2] = (f16)a.z; h[3] = (f16)a.w;
    h[4] = (f16)b.x; h[5] = (f16)b.y; h[6] = (f16)b.z; h[7] = (f16)b.w;
    *(half8*)(xb + idx) = h;
    return;
  }
  __shared__ float tile[32][33];
  const int rem0 = bid - 2048;
  const int mat = rem0 >> 10;
  const int rem = rem0 & 1023;
  const int kt = (rem >> 5) * 32;
  const int nt = (rem & 31) * 32;
  const float* W = mat == 0 ? W0 : mat == 1 ? W1 : mat == 2 ? W2 : W3;
  f16* T = mat == 0 ? T0 : mat == 1 ? T1 : mat == 2 ? T2 : T3;
  const int tid = threadIdx.x;
  const int r = tid >> 3;
  const int c4 = (tid & 7) * 4;
  const float4 v = *(const float4*)(W + (size_t)(kt + r) * 1024 + nt + c4);
  tile[r][c4 + 0] = v.x; tile[r][c4 + 1] = v.y;
  tile[r][c4 + 2] = v.z; tile[r][c4 + 3] = v.w;
  __syncthreads();
  half4 o;
  #pragma unroll
  for (int e = 0; e < 4; e++) o[e] = (f16)tile[c4 + e][r];
  *(half4*)(T + (size_t)(nt + r) * 1024 + kt + c4) = o;
}

// ---------------------------------------------------------------------------
// 4-wave 128x128 GEMM core, 32x32x16 MFMA: wave tile 64x64 = 2x2 32-tiles.
// BK=64 (4 k-slices of 16). Per K-step/wave: 8 gload16, 16 ds_read_b128,
// 16 MFMA. Frag layout: A/B row = lane&31, k = (lane>>5)*8 + e.
__device__ __forceinline__ void gemm_core4(const f16* __restrict__ A,
                                           const f16* __restrict__ Bt,
                                           int m0, int n0,
                                           f16* As, f16* Bs,
                                           f32x16 acc[2][2]) {
  const int tid = threadIdx.x;
  const int lane = tid & 63, wave = tid >> 6;
  const int wm = wave >> 1, wn = wave & 1;
  const int r32 = lane & 31, hi = lane >> 5;
  const int sx = (r32 & 7) << 4;

  const int srow = wave * 32 + (lane >> 3);
  const int cc = lane & 7;
  const size_t go = (size_t)srow * 1024 + (size_t)((cc ^ (srow & 7)) * 8);
  const f16* ag = A + (size_t)m0 * 1024 + go;
  const f16* bg = Bt + (size_t)n0 * 1024 + go;
  f16* la = As + wave * 2048;
  f16* lb = Bs + wave * 2048;

  #pragma unroll
  for (int i = 0; i < 2; i++)
    #pragma unroll
    for (int j = 0; j < 2; j++)
      #pragma unroll
      for (int e = 0; e < 16; e++) acc[i][j][e] = 0.f;

  for (int kt = 0; kt < 1024; kt += 64) {
    #pragma unroll
    for (int t = 0; t < 4; t++) {
      gload16(ag + kt + t * 8192, la + t * 512);
      gload16(bg + kt + t * 8192, lb + t * 512);
    }
    __syncthreads();
    const char* Ab = (const char*)As;
    const char* Bb = (const char*)Bs;
    #pragma unroll
    for (int ks = 0; ks < 4; ks++) {
      const int co = (ks * 32 + hi * 16) ^ sx;   // k byte offset, 0..127
      half8 af[2], bf[2];
      #pragma unroll
      for (int mb = 0; mb < 2; mb++)
        af[mb] = *(const half8*)(Ab + (wm * 64 + mb * 32 + r32) * 128 + co);
      #pragma unroll
      for (int nb = 0; nb < 2; nb++)
        bf[nb] = *(const half8*)(Bb + (wn * 64 + nb * 32 + r32) * 128 + co);
      #pragma unroll
      for (int mb = 0; mb < 2; mb++)
        #pragma unroll
        for (int nb = 0; nb < 2; nb++)
          acc[mb][nb] = MFMA32(af[mb], bf[nb], acc[mb][nb]);
    }
    __syncthreads();
  }
}

// ---------------------------------------------------------------------------
// Fused QKV: grid 768 = 32m x 24n, 256 threads, 3 blocks/CU.
// C/D: col = lane&31, row = (reg&3) + 8*(reg>>2) + 4*(lane>>5).
__global__ __launch_bounds__(256, 3) void gemm_qkv_kernel(
    const f16* __restrict__ xb, const f16* __restrict__ wt,
    const float* __restrict__ bq, const float* __restrict__ bk,
    const float* __restrict__ bv,
    f16* __restrict__ qo, f16* __restrict__ ko, f16* __restrict__ vt) {
  __shared__ __align__(16) f16 As[128 * 64];
  __shared__ __align__(16) f16 Bs[128 * 64];
  const int wg = (blockIdx.x & 7) * 96 + (blockIdx.x >> 3);
  const int m0 = (wg & 31) * 128;
  const int n0 = (wg >> 5) * 128;
  f32x16 acc[2][2];
  gemm_core4(xb, wt, m0, n0, As, Bs, acc);

  const int lane = threadIdx.x & 63, wave = threadIdx.x >> 6;
  const int wm = wave >> 1, wn = wave & 1;
  const int r32 = lane & 31, hi = lane >> 5;
  const int matid = n0 >> 10;
  const int nc0 = n0 & 1023;
  const float* bias = matid == 0 ? bq : matid == 1 ? bk : bv;
  if (matid < 2) {
    f16* out = matid == 0 ? qo : ko;
    #pragma unroll
    for (int mb = 0; mb < 2; mb++)
      #pragma unroll
      for (int nb = 0; nb < 2; nb++) {
        const int col = nc0 + wn * 64 + nb * 32 + r32;
        const float bb = bias[col];
        #pragma unroll
        for (int reg = 0; reg < 16; reg++) {
          const int row = m0 + wm * 64 + mb * 32 +
                          (reg & 3) + 8 * (reg >> 2) + 4 * hi;
          out[(size_t)row * 1024 + col] = (f16)(acc[mb][nb][reg] + bb);
        }
      }
  } else {
    // V transposed per head: Vt[b][h][d][t]; reg-quad -> 4 consecutive t
    #pragma unroll
    for (int mb = 0; mb < 2; mb++)
      #pragma unroll
      for (int nb = 0; nb < 2; nb++) {
        const int col = nc0 + wn * 64 + nb * 32 + r32;
        const int h = col >> 6, d = col & 63;
        const float bb = bias[col];
        #pragma unroll
        for (int r2 = 0; r2 < 4; r2++) {
          const int row = m0 + wm * 64 + mb * 32 + 8 * r2 + 4 * hi;
          const int b = row >> 11, t = row & 2047;
          half4 vv;
          #pragma unroll
          for (int q = 0; q < 4; q++)
            vv[q] = (f16)(acc[mb][nb][r2 * 4 + q] + bb);
          *(half4*)(vt + (((size_t)(b * 16 + h)) * 64 + d) * 2048 + t) = vv;
        }
      }
  }
}

// ---------------------------------------------------------------------------
// Output projection: 128x64 tiles, grid 512, 256 threads, 4 waves (2M x 2N),
// wave tile 64x32 = 2x1 32-tiles, 32x32x16 MFMA.
__global__ __launch_bounds__(256, 4) void gemm_o_kernel(
    const f16* __restrict__ ao, const f16* __restrict__ wot,
    const float* __restrict__ bo, float* __restrict__ out) {
  __shared__ __align__(16) f16 As[128 * 64];
  __shared__ __align__(16) f16 Bs[64 * 64];
  const int wg = (blockIdx.x & 7) * 64 + (blockIdx.x >> 3);
  const int m0 = (wg & 31) * 128;
  const int n0 = (wg >> 5) * 64;

  const int tid = threadIdx.x;
  const int lane = tid & 63, wave = tid >> 6;
  const int wm = wave >> 1, wn = wave & 1;
  const int r32 = lane & 31, hi = lane >> 5;
  const int sx = (r32 & 7) << 4;

  const int cc = lane & 7;
  const int srA = wave * 32 + (lane >> 3);
  const int srB = wave * 16 + (lane >> 3);
  const size_t goA = (size_t)srA * 1024 + (size_t)((cc ^ (srA & 7)) * 8);
  const size_t goB = (size_t)srB * 1024 + (size_t)((cc ^ (srB & 7)) * 8);
  const f16* ag = ao + (size_t)m0 * 1024 + goA;
  const f16* bg = wot + (size_t)n0 * 1024 + goB;
  f16* la = As + wave * 2048;
  f16* lb = Bs + wave * 1024;

  f32x16 acc[2];
  #pragma unroll
  for (int i = 0; i < 2; i++)
    #pragma unroll
    for (int e = 0; e < 16; e++) acc[i][e] = 0.f;

  for (int kt = 0; kt < 1024; kt += 64) {
    #pragma unroll
    for (int t = 0; t < 4; t++) gload16(ag + kt + t * 8192, la + t * 512);
    #pragma unroll
    for (int t = 0; t < 2; t++) gload16(bg + kt + t * 8192, lb + t * 512);
    __syncthreads();
    const char* Ab = (const char*)As;
    const char* Bb = (const char*)Bs;
    #pragma unroll
    for (int ks = 0; ks < 4; ks++) {
      const int co = (ks * 32 + hi * 16) ^ sx;
      half8 af[2], bf;
      #pragma unroll
      for (int mb = 0; mb < 2; mb++)
        af[mb] = *(const half8*)(Ab + (wm * 64 + mb * 32 + r32) * 128 + co);
      bf = *(const half8*)(Bb + (wn * 32 + r32) * 128 + co);
      #pragma unroll
      for (int mb = 0; mb < 2; mb++) acc[mb] = MFMA32(af[mb], bf, acc[mb]);
    }
    __syncthreads();
  }

  const int col = n0 + wn * 32 + r32;
  const float bb = bo[col];
  #pragma unroll
  for (int mb = 0; mb < 2; mb++)
    #pragma unroll
    for (int reg = 0; reg < 16; reg++) {
      const int row = m0 + wm * 64 + mb * 32 + (reg & 3) + 8 * (reg >> 2) + 4 * hi;
      out[(size_t)row * 1024 + col] = acc[mb][reg] + bb;
    }
}

// ---------------------------------------------------------------------------
// Sliding-window attention v4: QBLK=128 (4 waves x 32 q-rows), KVBLK=64.
// grid 512 = 32 bh * 16 qt. (unchanged from round 7)
__global__ __launch_bounds__(256, 3) void attn_kernel(
    const f16* __restrict__ Q, const f16* __restrict__ K,
    const f16* __restrict__ Vt, f16* __restrict__ Ao) {
  __shared__ __align__(16) f16 Ks[2][64 * 64];
  __shared__ __align__(16) f16 Vs[2][64 * 64];
  __shared__ __align__(16) f16 Ps[4][32][72];

  const int tid = threadIdx.x, lane = tid & 63, wave = tid >> 6;
  const int fr = lane & 15, g = lane >> 4;
  const int qt = blockIdx.x & 15, bh = blockIdx.x >> 4;
  const int b = bh >> 4, h = bh & 15;
  const int q0 = qt * 128;
  const int qr = q0 + wave * 32;

  const f16* Qb = Q + ((size_t)(b * 2048 + qr)) * 1024 + h * 64;
  half8 qf[2][2];
  #pragma unroll
  for (int mc = 0; mc < 2; mc++)
    #pragma unroll
    for (int kk = 0; kk < 2; kk++)
      qf[mc][kk] =
          *(const half8*)(Qb + (size_t)(mc * 16 + fr) * 1024 + kk * 32 + g * 8);

  const char* Kg = (const char*)(K + ((size_t)(b * 2048)) * 1024 + h * 64);
  const char* Vg = (const char*)(Vt + ((size_t)(b * 16 + h)) * 64 * 2048);

  const int sr = wave * 16 + (lane >> 3);
  const int sco = ((lane & 7) ^ (sr & 7)) << 4;

  auto stageKV = [&](int buf, int jt) {
    #pragma unroll
    for (int t = 0; t < 2; t++) {
      gload16(Kg + (size_t)(jt + sr + t * 8) * 2048 + sco,
              (f16*)Ks[buf] + wave * 1024 + t * 512);
      gload16(Vg + (size_t)(sr + t * 8) * 4096 + (size_t)jt * 2 + sco,
              (f16*)Vs[buf] + wave * 1024 + t * 512);
    }
  };

  const int t0 = q0 >= 256 ? (q0 - 256) >> 6 : 0;
  const int t1 = (q0 + 127) >> 6;

  f32x4 O[2][4];
  #pragma unroll
  for (int mc = 0; mc < 2; mc++)
    #pragma unroll
    for (int nt = 0; nt < 4; nt++) O[mc][nt] = (f32x4){0.f, 0.f, 0.f, 0.f};
  float lsum[2][4] = {{0.f, 0.f, 0.f, 0.f}, {0.f, 0.f, 0.f, 0.f}};

  stageKV(0, t0 * 64);
  __syncthreads();

  for (int tt = t0; tt <= t1; ++tt) {
    const int cur = (tt - t0) & 1;
    if (tt < t1) stageKV(cur ^ 1, (tt + 1) * 64);
    const int jt = tt * 64;
    const bool alive = (jt <= qr + 31) && (jt + 63 >= qr - 256);
    if (alive) {
      const char* Kb = (const char*)Ks[cur];
      const char* Vb = (const char*)Vs[cur];
      f32x4 s[2][4];
      #pragma unroll
      for (int jj = 0; jj < 4; ++jj) {
        const int kj = jj * 16 + fr;
        const char* krow = Kb + kj * 128;
        const int kswz = (kj & 7) << 4;
        const half8 kf0 = *(const half8*)(krow + ((g * 16) ^ kswz));
        const half8 kf1 = *(const half8*)(krow + ((64 + g * 16) ^ kswz));
        #pragma unroll
        for (int mc = 0; mc < 2; mc++) {
          f32x4 z = (f32x4){0.f, 0.f, 0.f, 0.f};
          z = MFMA16(qf[mc][0], kf0, z);
          z = MFMA16(qf[mc][1], kf1, z);
          s[mc][jj] = z;
        }
      }
      #pragma unroll
      for (int mc = 0; mc < 2; mc++) {
        const int eb = qr + mc * 16 + g * 4 - jt - fr;
        #pragma unroll
        for (int jj = 0; jj < 4; ++jj) {
          #pragma unroll
          for (int r = 0; r < 4; ++r) {
            const float a = __expf(s[mc][jj][r] * 0.125f - 3.0f);
            const float p = ((unsigned)(eb + r - jj * 16) <= 256u) ? a : 0.f;
            lsum[mc][r] += p;
            Ps[wave][mc * 16 + g * 4 + r][jj * 16 + fr] = (f16)p;
          }
        }
      }
      #pragma unroll
      for (int ks = 0; ks < 2; ++ks) {
        const half8 pa0 = *(const half8*)(&Ps[wave][fr][ks * 32 + g * 8]);
        const half8 pa1 = *(const half8*)(&Ps[wave][16 + fr][ks * 32 + g * 8]);
        #pragma unroll
        for (int nt = 0; nt < 4; ++nt) {
          const int vd = nt * 16 + fr;
          const half8 vf = *(const half8*)(
              Vb + vd * 128 + ((ks * 64 + g * 16) ^ ((vd & 7) << 4)));
          O[0][nt] = MFMA16(pa0, vf, O[0][nt]);
          O[1][nt] = MFMA16(pa1, vf, O[1][nt]);
        }
      }
    }
    __syncthreads();
  }

  float inv[2][4];
  #pragma unroll
  for (int mc = 0; mc < 2; mc++)
    #pragma unroll
    for (int r = 0; r < 4; ++r) {
      float s = lsum[mc][r];
      s += __shfl_xor(s, 1);
      s += __shfl_xor(s, 2);
      s += __shfl_xor(s, 4);
      s += __shfl_xor(s, 8);
      inv[mc][r] = 1.0f / s;
    }
  f16* Aout = Ao + ((size_t)(b * 2048 + qr)) * 1024 + h * 64;
  #pragma unroll
  for (int mc = 0; mc < 2; mc++)
    #pragma unroll
    for (int nt = 0; nt < 4; ++nt)
      #pragma unroll
      for (int r = 0; r < 4; ++r)
        Aout[(size_t)(mc * 16 + g * 4 + r) * 1024 + nt * 16 + fr] =
            (f16)(O[mc][nt][r] * inv[mc][r]);
}

// ---------------------------------------------------------------------------
extern "C" void kernel_launch(void* const* d_in, const int* in_sizes, int n_in,
                              void* d_out, int out_size, void* d_ws,
                              size_t ws_size, hipStream_t stream) {
  const float* x  = (const float*)d_in[0];
  const float* Wq = (const float*)d_in[1];
  const float* bq = (const float*)d_in[2];
  const float* Wk = (const float*)d_in[3];
  const float* bk = (const float*)d_in[4];
  const float* Wv = (const float*)d_in[5];
  const float* bv = (const float*)d_in[6];
  const float* Wo = (const float*)d_in[7];
  const float* bo = (const float*)d_in[8];

  char* w = (char*)d_ws;
  f16* xb  = (f16*)(w);                          // 8 MiB  : x in f16
  f16* wqt = (f16*)(w + ((size_t)8 << 20));      // 2 MiB  : Wq^T f16
  f16* wkt = (f16*)(w + ((size_t)10 << 20));     //        (wq/wk/wv contiguous)
  f16* wvt = (f16*)(w + ((size_t)12 << 20));
  f16* wot = (f16*)(w + ((size_t)14 << 20));
  f16* q   = (f16*)(w + ((size_t)16 << 20));     // 8 MiB  : Q [4096][1024]
  f16* kk  = (f16*)(w + ((size_t)24 << 20));     // 8 MiB  : K
  f16* vt  = (f16*)(w + ((size_t)32 << 20));     // 8 MiB  : V^T [b][h][d][t]
  f16* ao  = (f16*)(w + ((size_t)40 << 20));     // 8 MiB  : attn out

  prep_kernel<<<6144, 256, 0, stream>>>(x, xb, Wq, Wk, Wv, Wo,
                                        wqt, wkt, wvt, wot);
  gemm_qkv_kernel<<<768, 256, 0, stream>>>(xb, wqt, bq, bk, bv, q, kk, vt);
  attn_kernel<<<512, 256, 0, stream>>>(q, kk, vt, ao);
  gemm_o_kernel<<<512, 256, 0, stream>>>(ao, wot, bo, (float*)d_out);
}

// Round 9
// 79.409 us; speedup vs baseline: 1.0676x; 1.0676x over previous
//
#include <hip/hip_runtime.h>

// ---------------------------------------------------------------------------
// SlidingWindowAttention on MI355X (gfx950)
// B=2 T=2048 C=1024 H=16 D=64 WINDOW=256
// f16 16x16x32 MFMA everywhere (32x32x16 regressed: 4-way LDS conflicts vs
// the 3-bit XOR swizzle -- row-span must be <=16 with (row&7)<<4).
// ---------------------------------------------------------------------------

typedef _Float16 f16;
typedef _Float16 half8 __attribute__((ext_vector_type(8)));
typedef _Float16 half4 __attribute__((ext_vector_type(4)));
typedef float    f32x4 __attribute__((ext_vector_type(4)));

#define MFMA16(a, b, c) __builtin_amdgcn_mfma_f32_16x16x32_f16((a), (b), (c), 0, 0, 0)

__device__ __forceinline__ void gload16(const void* g, void* l) {
  __builtin_amdgcn_global_load_lds(
      (const __attribute__((address_space(1))) void*)g,
      (__attribute__((address_space(3))) void*)l, 16, 0, 0);
}

// ---------------------------------------------------------------------------
// prep: blocks 0..2047 convert x f32->f16; blocks 2048..6143 transpose weights
__global__ __launch_bounds__(256) void prep_kernel(
    const float* __restrict__ x, f16* __restrict__ xb,
    const float* __restrict__ W0, const float* __restrict__ W1,
    const float* __restrict__ W2, const float* __restrict__ W3,
    f16* __restrict__ T0, f16* __restrict__ T1,
    f16* __restrict__ T2, f16* __restrict__ T3) {
  const int bid = blockIdx.x;
  if (bid < 2048) {
    const int idx = (bid * 256 + threadIdx.x) * 8;
    const float4 a = *(const float4*)(x + idx);
    const float4 b = *(const float4*)(x + idx + 4);
    half8 h;
    h[0] = (f16)a.x; h[1] = (f16)a.y; h[2] = (f16)a.z; h[3] = (f16)a.w;
    h[4] = (f16)b.x; h[5] = (f16)b.y; h[6] = (f16)b.z; h[7] = (f16)b.w;
    *(half8*)(xb + idx) = h;
    return;
  }
  __shared__ float tile[32][33];
  const int rem0 = bid - 2048;
  const int mat = rem0 >> 10;
  const int rem = rem0 & 1023;
  const int kt = (rem >> 5) * 32;
  const int nt = (rem & 31) * 32;
  const float* W = mat == 0 ? W0 : mat == 1 ? W1 : mat == 2 ? W2 : W3;
  f16* T = mat == 0 ? T0 : mat == 1 ? T1 : mat == 2 ? T2 : T3;
  const int tid = threadIdx.x;
  const int r = tid >> 3;
  const int c4 = (tid & 7) * 4;
  const float4 v = *(const float4*)(W + (size_t)(kt + r) * 1024 + nt + c4);
  tile[r][c4 + 0] = v.x; tile[r][c4 + 1] = v.y;
  tile[r][c4 + 2] = v.z; tile[r][c4 + 3] = v.w;
  __syncthreads();
  if (tid < 128) {                       // half8 stores: 16B, half the count
    const int n = tid >> 2;
    const int k8 = (tid & 3) * 8;
    half8 o;
    #pragma unroll
    for (int e = 0; e < 8; e++) o[e] = (f16)tile[k8 + e][n];
    *(half8*)(T + (size_t)(nt + n) * 1024 + kt + k8) = o;
  }
}

// ---------------------------------------------------------------------------
// 4-wave 128x128 GEMM core: wave tile 64x64, BK=64, 16 K-steps. (round-7)
__device__ __forceinline__ void gemm_core4(const f16* __restrict__ A,
                                           const f16* __restrict__ Bt,
                                           int m0, int n0,
                                           f16* As, f16* Bs,
                                           f32x4 acc[4][4]) {
  const int tid = threadIdx.x;
  const int lane = tid & 63, wave = tid >> 6;
  const int wm = wave >> 1, wn = wave & 1;
  const int fr = lane & 15, fg = lane >> 4;
  const int sx = (fr & 7) << 4;

  const int srow = wave * 32 + (lane >> 3);
  const int cc = lane & 7;
  const size_t go = (size_t)srow * 1024 + (size_t)((cc ^ (srow & 7)) * 8);
  const f16* ag = A + (size_t)m0 * 1024 + go;
  const f16* bg = Bt + (size_t)n0 * 1024 + go;
  f16* la = As + wave * 2048;
  f16* lb = Bs + wave * 2048;

  #pragma unroll
  for (int i = 0; i < 4; i++)
    #pragma unroll
    for (int j = 0; j < 4; j++) acc[i][j] = (f32x4){0.f, 0.f, 0.f, 0.f};

  for (int kt = 0; kt < 1024; kt += 64) {
    #pragma unroll
    for (int t = 0; t < 4; t++) {
      gload16(ag + kt + t * 8192, la + t * 512);
      gload16(bg + kt + t * 8192, lb + t * 512);
    }
    __syncthreads();
    const char* Ab = (const char*)As;
    const char* Bb = (const char*)Bs;
    #pragma unroll
    for (int kk = 0; kk < 2; kk++) {
      half8 af[4], bf[4];
      const int co = (kk * 64 + fg * 16) ^ sx;
      #pragma unroll
      for (int mf = 0; mf < 4; mf++)
        af[mf] = *(const half8*)(Ab + (wm * 64 + mf * 16 + fr) * 128 + co);
      #pragma unroll
      for (int nf = 0; nf < 4; nf++)
        bf[nf] = *(const half8*)(Bb + (wn * 64 + nf * 16 + fr) * 128 + co);
      #pragma unroll
      for (int mf = 0; mf < 4; mf++)
        #pragma unroll
        for (int nf = 0; nf < 4; nf++)
          acc[mf][nf] = MFMA16(af[mf], bf[nf], acc[mf][nf]);
    }
    __syncthreads();
  }
}

// ---------------------------------------------------------------------------
// Fused QKV: grid 768 = 32m x 24n, 256 threads, 3 blocks/CU.
__global__ __launch_bounds__(256, 3) void gemm_qkv_kernel(
    const f16* __restrict__ xb, const f16* __restrict__ wt,
    const float* __restrict__ bq, const float* __restrict__ bk,
    const float* __restrict__ bv,
    f16* __restrict__ qo, f16* __restrict__ ko, f16* __restrict__ vt) {
  __shared__ __align__(16) f16 As[128 * 64];
  __shared__ __align__(16) f16 Bs[128 * 64];
  const int wg = (blockIdx.x & 7) * 96 + (blockIdx.x >> 3);
  const int m0 = (wg & 31) * 128;
  const int n0 = (wg >> 5) * 128;
  f32x4 acc[4][4];
  gemm_core4(xb, wt, m0, n0, As, Bs, acc);

  const int lane = threadIdx.x & 63, wave = threadIdx.x >> 6;
  const int wm = wave >> 1, wn = wave & 1;
  const int fr = lane & 15, fg = lane >> 4;
  const int matid = n0 >> 10;
  const int nc0 = n0 & 1023;
  const float* bias = matid == 0 ? bq : matid == 1 ? bk : bv;
  if (matid < 2) {
    f16* out = matid == 0 ? qo : ko;
    #pragma unroll
    for (int mf = 0; mf < 4; mf++)
      #pragma unroll
      for (int nf = 0; nf < 4; nf++) {
        const int col = nc0 + wn * 64 + nf * 16 + fr;
        const float bb = bias[col];
        #pragma unroll
        for (int r = 0; r < 4; r++) {
          const int row = m0 + wm * 64 + mf * 16 + fg * 4 + r;
          out[(size_t)row * 1024 + col] = (f16)(acc[mf][nf][r] + bb);
        }
      }
  } else {
    #pragma unroll
    for (int mf = 0; mf < 4; mf++)
      #pragma unroll
      for (int nf = 0; nf < 4; nf++) {
        const int row = m0 + wm * 64 + mf * 16 + fg * 4;
        const int col = nc0 + wn * 64 + nf * 16 + fr;
        const int b = row >> 11, t = row & 2047;
        const int h = col >> 6, d = col & 63;
        const float bb = bias[col];
        half4 vv;
        #pragma unroll
        for (int r = 0; r < 4; r++) vv[r] = (f16)(acc[mf][nf][r] + bb);
        *(half4*)(vt + (((size_t)(b * 16 + h)) * 64 + d) * 2048 + t) = vv;
      }
  }
}

// ---------------------------------------------------------------------------
// Output projection: 128x64 tiles, grid 512, 256 threads, 4 waves (2M x 2N).
__global__ __launch_bounds__(256, 4) void gemm_o_kernel(
    const f16* __restrict__ ao, const f16* __restrict__ wot,
    const float* __restrict__ bo, float* __restrict__ out) {
  __shared__ __align__(16) f16 As[128 * 64];
  __shared__ __align__(16) f16 Bs[64 * 64];
  const int wg = (blockIdx.x & 7) * 64 + (blockIdx.x >> 3);
  const int m0 = (wg & 31) * 128;
  const int n0 = (wg >> 5) * 64;

  const int tid = threadIdx.x;
  const int lane = tid & 63, wave = tid >> 6;
  const int wm = wave >> 1, wn = wave & 1;
  const int fr = lane & 15, fg = lane >> 4;
  const int sx = (fr & 7) << 4;

  const int cc = lane & 7;
  const int srA = wave * 32 + (lane >> 3);
  const int srB = wave * 16 + (lane >> 3);
  const size_t goA = (size_t)srA * 1024 + (size_t)((cc ^ (srA & 7)) * 8);
  const size_t goB = (size_t)srB * 1024 + (size_t)((cc ^ (srB & 7)) * 8);
  const f16* ag = ao + (size_t)m0 * 1024 + goA;
  const f16* bg = wot + (size_t)n0 * 1024 + goB;
  f16* la = As + wave * 2048;
  f16* lb = Bs + wave * 1024;

  f32x4 acc[4][2];
  #pragma unroll
  for (int i = 0; i < 4; i++)
    #pragma unroll
    for (int j = 0; j < 2; j++) acc[i][j] = (f32x4){0.f, 0.f, 0.f, 0.f};

  for (int kt = 0; kt < 1024; kt += 64) {
    #pragma unroll
    for (int t = 0; t < 4; t++) gload16(ag + kt + t * 8192, la + t * 512);
    #pragma unroll
    for (int t = 0; t < 2; t++) gload16(bg + kt + t * 8192, lb + t * 512);
    __syncthreads();
    const char* Ab = (const char*)As;
    const char* Bb = (const char*)Bs;
    #pragma unroll
    for (int kk = 0; kk < 2; kk++) {
      half8 af[4], bf[2];
      const int co = (kk * 64 + fg * 16) ^ sx;
      #pragma unroll
      for (int mf = 0; mf < 4; mf++)
        af[mf] = *(const half8*)(Ab + (wm * 64 + mf * 16 + fr) * 128 + co);
      #pragma unroll
      for (int nf = 0; nf < 2; nf++)
        bf[nf] = *(const half8*)(Bb + (wn * 32 + nf * 16 + fr) * 128 + co);
      #pragma unroll
      for (int mf = 0; mf < 4; mf++)
        #pragma unroll
        for (int nf = 0; nf < 2; nf++)
          acc[mf][nf] = MFMA16(af[mf], bf[nf], acc[mf][nf]);
    }
    __syncthreads();
  }

  #pragma unroll
  for (int mf = 0; mf < 4; mf++)
    #pragma unroll
    for (int nf = 0; nf < 2; nf++) {
      const int col = n0 + wn * 32 + nf * 16 + fr;
      const float bb = bo[col];
      #pragma unroll
      for (int r = 0; r < 4; r++) {
        const int row = m0 + wm * 64 + mf * 16 + fg * 4 + r;
        out[(size_t)row * 1024 + col] = acc[mf][nf][r] + bb;
      }
    }
}

// ---------------------------------------------------------------------------
// Sliding-window attention v4 + XCD-clustered bh: QBLK=128, KVBLK=64.
// grid 512; wg swizzle puts all 16 q-tiles of a bh (512KB K/V) on one XCD.
__global__ __launch_bounds__(256, 3) void attn_kernel(
    const f16* __restrict__ Q, const f16* __restrict__ K,
    const f16* __restrict__ Vt, f16* __restrict__ Ao) {
  __shared__ __align__(16) f16 Ks[2][64 * 64];
  __shared__ __align__(16) f16 Vs[2][64 * 64];
  __shared__ __align__(16) f16 Ps[4][32][72];

  const int tid = threadIdx.x, lane = tid & 63, wave = tid >> 6;
  const int fr = lane & 15, g = lane >> 4;
  const int wg = (blockIdx.x & 7) * 64 + (blockIdx.x >> 3);  // XCD-clustered
  const int qt = wg & 15, bh = wg >> 4;
  const int b = bh >> 4, h = bh & 15;
  const int q0 = qt * 128;
  const int qr = q0 + wave * 32;

  const f16* Qb = Q + ((size_t)(b * 2048 + qr)) * 1024 + h * 64;
  half8 qf[2][2];
  #pragma unroll
  for (int mc = 0; mc < 2; mc++)
    #pragma unroll
    for (int kk = 0; kk < 2; kk++)
      qf[mc][kk] =
          *(const half8*)(Qb + (size_t)(mc * 16 + fr) * 1024 + kk * 32 + g * 8);

  const char* Kg = (const char*)(K + ((size_t)(b * 2048)) * 1024 + h * 64);
  const char* Vg = (const char*)(Vt + ((size_t)(b * 16 + h)) * 64 * 2048);

  const int sr = wave * 16 + (lane >> 3);
  const int sco = ((lane & 7) ^ (sr & 7)) << 4;

  auto stageKV = [&](int buf, int jt) {
    #pragma unroll
    for (int t = 0; t < 2; t++) {
      gload16(Kg + (size_t)(jt + sr + t * 8) * 2048 + sco,
              (f16*)Ks[buf] + wave * 1024 + t * 512);
      gload16(Vg + (size_t)(sr + t * 8) * 4096 + (size_t)jt * 2 + sco,
              (f16*)Vs[buf] + wave * 1024 + t * 512);
    }
  };

  const int t0 = q0 >= 256 ? (q0 - 256) >> 6 : 0;
  const int t1 = (q0 + 127) >> 6;

  f32x4 O[2][4];
  #pragma unroll
  for (int mc = 0; mc < 2; mc++)
    #pragma unroll
    for (int nt = 0; nt < 4; nt++) O[mc][nt] = (f32x4){0.f, 0.f, 0.f, 0.f};
  float lsum[2][4] = {{0.f, 0.f, 0.f, 0.f}, {0.f, 0.f, 0.f, 0.f}};

  stageKV(0, t0 * 64);
  __syncthreads();

  for (int tt = t0; tt <= t1; ++tt) {
    const int cur = (tt - t0) & 1;
    if (tt < t1) stageKV(cur ^ 1, (tt + 1) * 64);
    const int jt = tt * 64;
    const bool alive = (jt <= qr + 31) && (jt + 63 >= qr - 256);
    if (alive) {
      const char* Kb = (const char*)Ks[cur];
      const char* Vb = (const char*)Vs[cur];
      f32x4 s[2][4];
      #pragma unroll
      for (int jj = 0; jj < 4; ++jj) {
        const int kj = jj * 16 + fr;
        const char* krow = Kb + kj * 128;
        const int kswz = (kj & 7) << 4;
        const half8 kf0 = *(const half8*)(krow + ((g * 16) ^ kswz));
        const half8 kf1 = *(const half8*)(krow + ((64 + g * 16) ^ kswz));
        #pragma unroll
        for (int mc = 0; mc < 2; mc++) {
          f32x4 z = (f32x4){0.f, 0.f, 0.f, 0.f};
          z = MFMA16(qf[mc][0], kf0, z);
          z = MFMA16(qf[mc][1], kf1, z);
          s[mc][jj] = z;
        }
      }
      #pragma unroll
      for (int mc = 0; mc < 2; mc++) {
        const int eb = qr + mc * 16 + g * 4 - jt - fr;
        #pragma unroll
        for (int jj = 0; jj < 4; ++jj) {
          #pragma unroll
          for (int r = 0; r < 4; ++r) {
            const float a = __expf(s[mc][jj][r] * 0.125f - 3.0f);
            const float p = ((unsigned)(eb + r - jj * 16) <= 256u) ? a : 0.f;
            lsum[mc][r] += p;
            Ps[wave][mc * 16 + g * 4 + r][jj * 16 + fr] = (f16)p;
          }
        }
      }
      #pragma unroll
      for (int ks = 0; ks < 2; ++ks) {
        const half8 pa0 = *(const half8*)(&Ps[wave][fr][ks * 32 + g * 8]);
        const half8 pa1 = *(const half8*)(&Ps[wave][16 + fr][ks * 32 + g * 8]);
        #pragma unroll
        for (int nt = 0; nt < 4; ++nt) {
          const int vd = nt * 16 + fr;
          const half8 vf = *(const half8*)(
              Vb + vd * 128 + ((ks * 64 + g * 16) ^ ((vd & 7) << 4)));
          O[0][nt] = MFMA16(pa0, vf, O[0][nt]);
          O[1][nt] = MFMA16(pa1, vf, O[1][nt]);
        }
      }
    }
    __syncthreads();
  }

  float inv[2][4];
  #pragma unroll
  for (int mc = 0; mc < 2; mc++)
    #pragma unroll
    for (int r = 0; r < 4; ++r) {
      float s = lsum[mc][r];
      s += __shfl_xor(s, 1);
      s += __shfl_xor(s, 2);
      s += __shfl_xor(s, 4);
      s += __shfl_xor(s, 8);
      inv[mc][r] = 1.0f / s;
    }
  f16* Aout = Ao + ((size_t)(b * 2048 + qr)) * 1024 + h * 64;
  #pragma unroll
  for (int mc = 0; mc < 2; mc++)
    #pragma unroll
    for (int nt = 0; nt < 4; ++nt)
      #pragma unroll
      for (int r = 0; r < 4; ++r)
        Aout[(size_t)(mc * 16 + g * 4 + r) * 1024 + nt * 16 + fr] =
            (f16)(O[mc][nt][r] * inv[mc][r]);
}

// ---------------------------------------------------------------------------
extern "C" void kernel_launch(void* const* d_in, const int* in_sizes, int n_in,
                              void* d_out, int out_size, void* d_ws,
                              size_t ws_size, hipStream_t stream) {
  const float* x  = (const float*)d_in[0];
  const float* Wq = (const float*)d_in[1];
  const float* bq = (const float*)d_in[2];
  const float* Wk = (const float*)d_in[3];
  const float* bk = (const float*)d_in[4];
  const float* Wv = (const float*)d_in[5];
  const float* bv = (const float*)d_in[6];
  const float* Wo = (const float*)d_in[7];
  const float* bo = (const float*)d_in[8];

  char* w = (char*)d_ws;
  f16* xb  = (f16*)(w);                          // 8 MiB  : x in f16
  f16* wqt = (f16*)(w + ((size_t)8 << 20));      // 2 MiB  : Wq^T f16
  f16* wkt = (f16*)(w + ((size_t)10 << 20));     //        (wq/wk/wv contiguous)
  f16* wvt = (f16*)(w + ((size_t)12 << 20));
  f16* wot = (f16*)(w + ((size_t)14 << 20));
  f16* q   = (f16*)(w + ((size_t)16 << 20));     // 8 MiB  : Q [4096][1024]
  f16* kk  = (f16*)(w + ((size_t)24 << 20));     // 8 MiB  : K
  f16* vt  = (f16*)(w + ((size_t)32 << 20));     // 8 MiB  : V^T [b][h][d][t]
  f16* ao  = (f16*)(w + ((size_t)40 << 20));     // 8 MiB  : attn out

  prep_kernel<<<6144, 256, 0, stream>>>(x, xb, Wq, Wk, Wv, Wo,
                                        wqt, wkt, wvt, wot);
  gemm_qkv_kernel<<<768, 256, 0, stream>>>(xb, wqt, bq, bk, bv, q, kk, vt);
  attn_kernel<<<512, 256, 0, stream>>>(q, kk, vt, ao);
  gemm_o_kernel<<<512, 256, 0, stream>>>(ao, wot, bo, (float*)d_out);
}

// Round 10
// 78.688 us; speedup vs baseline: 1.0774x; 1.0092x over previous
//
#include <hip/hip_runtime.h>

// ---------------------------------------------------------------------------
// SlidingWindowAttention on MI355X (gfx950)
// B=2 T=2048 C=1024 H=16 D=64 WINDOW=256
// f16 16x16x32 MFMA. attn v5: swapped QK^T -> P stays in registers (no LDS
// round-trip); PV consumes P in permuted key order, V read as 2x b64.
// ---------------------------------------------------------------------------

typedef _Float16 f16;
typedef _Float16 half8 __attribute__((ext_vector_type(8)));
typedef _Float16 half4 __attribute__((ext_vector_type(4)));
typedef float    f32x4 __attribute__((ext_vector_type(4)));

#define MFMA16(a, b, c) __builtin_amdgcn_mfma_f32_16x16x32_f16((a), (b), (c), 0, 0, 0)

__device__ __forceinline__ void gload16(const void* g, void* l) {
  __builtin_amdgcn_global_load_lds(
      (const __attribute__((address_space(1))) void*)g,
      (__attribute__((address_space(3))) void*)l, 16, 0, 0);
}

// ---------------------------------------------------------------------------
// prep: blocks 0..2047 convert x f32->f16; blocks 2048..6143 transpose weights
__global__ __launch_bounds__(256) void prep_kernel(
    const float* __restrict__ x, f16* __restrict__ xb,
    const float* __restrict__ W0, const float* __restrict__ W1,
    const float* __restrict__ W2, const float* __restrict__ W3,
    f16* __restrict__ T0, f16* __restrict__ T1,
    f16* __restrict__ T2, f16* __restrict__ T3) {
  const int bid = blockIdx.x;
  if (bid < 2048) {
    const int idx = (bid * 256 + threadIdx.x) * 8;
    const float4 a = *(const float4*)(x + idx);
    const float4 b = *(const float4*)(x + idx + 4);
    half8 h;
    h[0] = (f16)a.x; h[1] = (f16)a.y; h[2] = (f16)a.z; h[3] = (f16)a.w;
    h[4] = (f16)b.x; h[5] = (f16)b.y; h[6] = (f16)b.z; h[7] = (f16)b.w;
    *(half8*)(xb + idx) = h;
    return;
  }
  __shared__ float tile[32][33];
  const int rem0 = bid - 2048;
  const int mat = rem0 >> 10;
  const int rem = rem0 & 1023;
  const int kt = (rem >> 5) * 32;
  const int nt = (rem & 31) * 32;
  const float* W = mat == 0 ? W0 : mat == 1 ? W1 : mat == 2 ? W2 : W3;
  f16* T = mat == 0 ? T0 : mat == 1 ? T1 : mat == 2 ? T2 : T3;
  const int tid = threadIdx.x;
  const int r = tid >> 3;
  const int c4 = (tid & 7) * 4;
  const float4 v = *(const float4*)(W + (size_t)(kt + r) * 1024 + nt + c4);
  tile[r][c4 + 0] = v.x; tile[r][c4 + 1] = v.y;
  tile[r][c4 + 2] = v.z; tile[r][c4 + 3] = v.w;
  __syncthreads();
  if (tid < 128) {
    const int n = tid >> 2;
    const int k8 = (tid & 3) * 8;
    half8 o;
    #pragma unroll
    for (int e = 0; e < 8; e++) o[e] = (f16)tile[k8 + e][n];
    *(half8*)(T + (size_t)(nt + n) * 1024 + kt + k8) = o;
  }
}

// ---------------------------------------------------------------------------
// 4-wave 128x128 GEMM core: wave tile 64x64, BK=64, 16 K-steps.
__device__ __forceinline__ void gemm_core4(const f16* __restrict__ A,
                                           const f16* __restrict__ Bt,
                                           int m0, int n0,
                                           f16* As, f16* Bs,
                                           f32x4 acc[4][4]) {
  const int tid = threadIdx.x;
  const int lane = tid & 63, wave = tid >> 6;
  const int wm = wave >> 1, wn = wave & 1;
  const int fr = lane & 15, fg = lane >> 4;
  const int sx = (fr & 7) << 4;

  const int srow = wave * 32 + (lane >> 3);
  const int cc = lane & 7;
  const size_t go = (size_t)srow * 1024 + (size_t)((cc ^ (srow & 7)) * 8);
  const f16* ag = A + (size_t)m0 * 1024 + go;
  const f16* bg = Bt + (size_t)n0 * 1024 + go;
  f16* la = As + wave * 2048;
  f16* lb = Bs + wave * 2048;

  #pragma unroll
  for (int i = 0; i < 4; i++)
    #pragma unroll
    for (int j = 0; j < 4; j++) acc[i][j] = (f32x4){0.f, 0.f, 0.f, 0.f};

  for (int kt = 0; kt < 1024; kt += 64) {
    #pragma unroll
    for (int t = 0; t < 4; t++) {
      gload16(ag + kt + t * 8192, la + t * 512);
      gload16(bg + kt + t * 8192, lb + t * 512);
    }
    __syncthreads();
    const char* Ab = (const char*)As;
    const char* Bb = (const char*)Bs;
    #pragma unroll
    for (int kk = 0; kk < 2; kk++) {
      half8 af[4], bf[4];
      const int co = (kk * 64 + fg * 16) ^ sx;
      #pragma unroll
      for (int mf = 0; mf < 4; mf++)
        af[mf] = *(const half8*)(Ab + (wm * 64 + mf * 16 + fr) * 128 + co);
      #pragma unroll
      for (int nf = 0; nf < 4; nf++)
        bf[nf] = *(const half8*)(Bb + (wn * 64 + nf * 16 + fr) * 128 + co);
      #pragma unroll
      for (int mf = 0; mf < 4; mf++)
        #pragma unroll
        for (int nf = 0; nf < 4; nf++)
          acc[mf][nf] = MFMA16(af[mf], bf[nf], acc[mf][nf]);
    }
    __syncthreads();
  }
}

// ---------------------------------------------------------------------------
// Fused QKV: grid 768 = 32m x 24n, 256 threads, 3 blocks/CU.
__global__ __launch_bounds__(256, 3) void gemm_qkv_kernel(
    const f16* __restrict__ xb, const f16* __restrict__ wt,
    const float* __restrict__ bq, const float* __restrict__ bk,
    const float* __restrict__ bv,
    f16* __restrict__ qo, f16* __restrict__ ko, f16* __restrict__ vt) {
  __shared__ __align__(16) f16 As[128 * 64];
  __shared__ __align__(16) f16 Bs[128 * 64];
  const int wg = (blockIdx.x & 7) * 96 + (blockIdx.x >> 3);
  const int m0 = (wg & 31) * 128;
  const int n0 = (wg >> 5) * 128;
  f32x4 acc[4][4];
  gemm_core4(xb, wt, m0, n0, As, Bs, acc);

  const int lane = threadIdx.x & 63, wave = threadIdx.x >> 6;
  const int wm = wave >> 1, wn = wave & 1;
  const int fr = lane & 15, fg = lane >> 4;
  const int matid = n0 >> 10;
  const int nc0 = n0 & 1023;
  const float* bias = matid == 0 ? bq : matid == 1 ? bk : bv;
  if (matid < 2) {
    f16* out = matid == 0 ? qo : ko;
    #pragma unroll
    for (int mf = 0; mf < 4; mf++)
      #pragma unroll
      for (int nf = 0; nf < 4; nf++) {
        const int col = nc0 + wn * 64 + nf * 16 + fr;
        const float bb = bias[col];
        #pragma unroll
        for (int r = 0; r < 4; r++) {
          const int row = m0 + wm * 64 + mf * 16 + fg * 4 + r;
          out[(size_t)row * 1024 + col] = (f16)(acc[mf][nf][r] + bb);
        }
      }
  } else {
    #pragma unroll
    for (int mf = 0; mf < 4; mf++)
      #pragma unroll
      for (int nf = 0; nf < 4; nf++) {
        const int row = m0 + wm * 64 + mf * 16 + fg * 4;
        const int col = nc0 + wn * 64 + nf * 16 + fr;
        const int b = row >> 11, t = row & 2047;
        const int h = col >> 6, d = col & 63;
        const float bb = bias[col];
        half4 vv;
        #pragma unroll
        for (int r = 0; r < 4; r++) vv[r] = (f16)(acc[mf][nf][r] + bb);
        *(half4*)(vt + (((size_t)(b * 16 + h)) * 64 + d) * 2048 + t) = vv;
      }
  }
}

// ---------------------------------------------------------------------------
// Output projection: 128x64 tiles, grid 512, 256 threads, 4 waves (2M x 2N).
__global__ __launch_bounds__(256, 4) void gemm_o_kernel(
    const f16* __restrict__ ao, const f16* __restrict__ wot,
    const float* __restrict__ bo, float* __restrict__ out) {
  __shared__ __align__(16) f16 As[128 * 64];
  __shared__ __align__(16) f16 Bs[64 * 64];
  const int wg = (blockIdx.x & 7) * 64 + (blockIdx.x >> 3);
  const int m0 = (wg & 31) * 128;
  const int n0 = (wg >> 5) * 64;

  const int tid = threadIdx.x;
  const int lane = tid & 63, wave = tid >> 6;
  const int wm = wave >> 1, wn = wave & 1;
  const int fr = lane & 15, fg = lane >> 4;
  const int sx = (fr & 7) << 4;

  const int cc = lane & 7;
  const int srA = wave * 32 + (lane >> 3);
  const int srB = wave * 16 + (lane >> 3);
  const size_t goA = (size_t)srA * 1024 + (size_t)((cc ^ (srA & 7)) * 8);
  const size_t goB = (size_t)srB * 1024 + (size_t)((cc ^ (srB & 7)) * 8);
  const f16* ag = ao + (size_t)m0 * 1024 + goA;
  const f16* bg = wot + (size_t)n0 * 1024 + goB;
  f16* la = As + wave * 2048;
  f16* lb = Bs + wave * 1024;

  f32x4 acc[4][2];
  #pragma unroll
  for (int i = 0; i < 4; i++)
    #pragma unroll
    for (int j = 0; j < 2; j++) acc[i][j] = (f32x4){0.f, 0.f, 0.f, 0.f};

  for (int kt = 0; kt < 1024; kt += 64) {
    #pragma unroll
    for (int t = 0; t < 4; t++) gload16(ag + kt + t * 8192, la + t * 512);
    #pragma unroll
    for (int t = 0; t < 2; t++) gload16(bg + kt + t * 8192, lb + t * 512);
    __syncthreads();
    const char* Ab = (const char*)As;
    const char* Bb = (const char*)Bs;
    #pragma unroll
    for (int kk = 0; kk < 2; kk++) {
      half8 af[4], bf[2];
      const int co = (kk * 64 + fg * 16) ^ sx;
      #pragma unroll
      for (int mf = 0; mf < 4; mf++)
        af[mf] = *(const half8*)(Ab + (wm * 64 + mf * 16 + fr) * 128 + co);
      #pragma unroll
      for (int nf = 0; nf < 2; nf++)
        bf[nf] = *(const half8*)(Bb + (wn * 32 + nf * 16 + fr) * 128 + co);
      #pragma unroll
      for (int mf = 0; mf < 4; mf++)
        #pragma unroll
        for (int nf = 0; nf < 2; nf++)
          acc[mf][nf] = MFMA16(af[mf], bf[nf], acc[mf][nf]);
    }
    __syncthreads();
  }

  #pragma unroll
  for (int mf = 0; mf < 4; mf++)
    #pragma unroll
    for (int nf = 0; nf < 2; nf++) {
      const int col = n0 + wn * 32 + nf * 16 + fr;
      const float bb = bo[col];
      #pragma unroll
      for (int r = 0; r < 4; r++) {
        const int row = m0 + wm * 64 + mf * 16 + fg * 4 + r;
        out[(size_t)row * 1024 + col] = acc[mf][nf][r] + bb;
      }
    }
}

// ---------------------------------------------------------------------------
// Sliding-window attention v5: QBLK=128, KVBLK=64, XCD-clustered bh.
// Swapped QK^T: s = mfma(K, Q) -> lane holds P[key jj*16+g*4+r][q mc*16+fr],
// i.e. consecutive keys of its own PV A-row -> P assembled in registers.
// PV uses permuted key order kappa(g,e); V B-frag read as 2x ds_read_b64 at
// the same permuted columns (sum over keys is permutation-invariant).
__global__ __launch_bounds__(256, 3) void attn_kernel(
    const f16* __restrict__ Q, const f16* __restrict__ K,
    const f16* __restrict__ Vt, f16* __restrict__ Ao) {
  __shared__ __align__(16) f16 Ks[2][64 * 64];   // [key][d] swizzled, 16KB
  __shared__ __align__(16) f16 Vs[2][64 * 64];   // [d][key] swizzled, 16KB

  const int tid = threadIdx.x, lane = tid & 63, wave = tid >> 6;
  const int fr = lane & 15, g = lane >> 4;
  const int wg = (blockIdx.x & 7) * 64 + (blockIdx.x >> 3);  // XCD-clustered
  const int qt = wg & 15, bh = wg >> 4;
  const int b = bh >> 4, h = bh & 15;
  const int q0 = qt * 128;
  const int qr = q0 + wave * 32;

  // Q fragments (B-operand): Q[q = mc*16+fr][d = kk*32 + g*8 + e]
  const f16* Qb = Q + ((size_t)(b * 2048 + qr)) * 1024 + h * 64;
  half8 qf[2][2];
  #pragma unroll
  for (int mc = 0; mc < 2; mc++)
    #pragma unroll
    for (int kk = 0; kk < 2; kk++)
      qf[mc][kk] =
          *(const half8*)(Qb + (size_t)(mc * 16 + fr) * 1024 + kk * 32 + g * 8);

  const char* Kg = (const char*)(K + ((size_t)(b * 2048)) * 1024 + h * 64);
  const char* Vg = (const char*)(Vt + ((size_t)(b * 16 + h)) * 64 * 2048);

  const int sr = wave * 16 + (lane >> 3);
  const int sco = ((lane & 7) ^ (sr & 7)) << 4;

  auto stageKV = [&](int buf, int jt) {
    #pragma unroll
    for (int t = 0; t < 2; t++) {
      gload16(Kg + (size_t)(jt + sr + t * 8) * 2048 + sco,
              (f16*)Ks[buf] + wave * 1024 + t * 512);
      gload16(Vg + (size_t)(sr + t * 8) * 4096 + (size_t)jt * 2 + sco,
              (f16*)Vs[buf] + wave * 1024 + t * 512);
    }
  };

  const int t0 = q0 >= 256 ? (q0 - 256) >> 6 : 0;
  const int t1 = (q0 + 127) >> 6;

  f32x4 O[2][4];
  #pragma unroll
  for (int mc = 0; mc < 2; mc++)
    #pragma unroll
    for (int nt = 0; nt < 4; nt++) O[mc][nt] = (f32x4){0.f, 0.f, 0.f, 0.f};
  float lsum[2] = {0.f, 0.f};

  stageKV(0, t0 * 64);
  __syncthreads();

  for (int tt = t0; tt <= t1; ++tt) {
    const int cur = (tt - t0) & 1;
    if (tt < t1) stageKV(cur ^ 1, (tt + 1) * 64);
    const int jt = tt * 64;
    const bool alive = (jt <= qr + 31) && (jt + 63 >= qr - 256);
    if (alive) {
      const char* Kb = (const char*)Ks[cur];
      const char* Vb = (const char*)Vs[cur];
      // QK^T swapped + in-register P assembly.
      // pa[mc][ks][e]: e<4 -> (jj=2ks, r=e); e>=4 -> (jj=2ks+1, r=e-4)
      half8 pa[2][2];
      #pragma unroll
      for (int jj = 0; jj < 4; ++jj) {
        const int kj = jj * 16 + fr;
        const char* krow = Kb + kj * 128;
        const int kswz = (kj & 7) << 4;
        const half8 kf0 = *(const half8*)(krow + ((g * 16) ^ kswz));
        const half8 kf1 = *(const half8*)(krow + ((64 + g * 16) ^ kswz));
        #pragma unroll
        for (int mc = 0; mc < 2; ++mc) {
          f32x4 z = (f32x4){0.f, 0.f, 0.f, 0.f};
          z = MFMA16(kf0, qf[mc][0], z);
          z = MFMA16(kf1, qf[mc][1], z);
          // i = qr+mc*16+fr, j = jt+jj*16+g*4+r
          const int eb = qr + mc * 16 + fr - jt - jj * 16 - g * 4;
          #pragma unroll
          for (int r = 0; r < 4; ++r) {
            const float a = __expf(z[r] * 0.125f - 3.0f);
            const float p = ((unsigned)(eb - r) <= 256u) ? a : 0.f;
            lsum[mc] += p;
            pa[mc][jj >> 1][(jj & 1) * 4 + r] = (f16)p;
          }
        }
      }
      // PV in permuted key order: kappa(g,e) = (2ks+(e>=4))*16 + 4g + (e&3)
      #pragma unroll
      for (int ks = 0; ks < 2; ++ks) {
        #pragma unroll
        for (int nt = 0; nt < 4; ++nt) {
          const int vd = nt * 16 + fr;
          const int sw = (vd & 7) << 4;
          const half4 vlo =
              *(const half4*)(Vb + vd * 128 + ((ks * 64 + 8 * g) ^ sw));
          const half4 vhi =
              *(const half4*)(Vb + vd * 128 + ((ks * 64 + 32 + 8 * g) ^ sw));
          half8 vf;
          vf[0] = vlo[0]; vf[1] = vlo[1]; vf[2] = vlo[2]; vf[3] = vlo[3];
          vf[4] = vhi[0]; vf[5] = vhi[1]; vf[6] = vhi[2]; vf[7] = vhi[3];
          O[0][nt] = MFMA16(pa[0][ks], vf, O[0][nt]);
          O[1][nt] = MFMA16(pa[1][ks], vf, O[1][nt]);
        }
      }
    }
    __syncthreads();
  }

  // lsum lives at lane q = mc*16+fr; O rows are q = mc*16+g*4+r.
  float inv[2][4];
  #pragma unroll
  for (int mc = 0; mc < 2; ++mc) {
    float t = lsum[mc];
    t += __shfl_xor(t, 16);
    t += __shfl_xor(t, 32);
    #pragma unroll
    for (int r = 0; r < 4; ++r) inv[mc][r] = 1.0f / __shfl(t, g * 4 + r);
  }
  f16* Aout = Ao + ((size_t)(b * 2048 + qr)) * 1024 + h * 64;
  #pragma unroll
  for (int mc = 0; mc < 2; ++mc)
    #pragma unroll
    for (int nt = 0; nt < 4; ++nt)
      #pragma unroll
      for (int r = 0; r < 4; ++r)
        Aout[(size_t)(mc * 16 + g * 4 + r) * 1024 + nt * 16 + fr] =
            (f16)(O[mc][nt][r] * inv[mc][r]);
}

// ---------------------------------------------------------------------------
extern "C" void kernel_launch(void* const* d_in, const int* in_sizes, int n_in,
                              void* d_out, int out_size, void* d_ws,
                              size_t ws_size, hipStream_t stream) {
  const float* x  = (const float*)d_in[0];
  const float* Wq = (const float*)d_in[1];
  const float* bq = (const float*)d_in[2];
  const float* Wk = (const float*)d_in[3];
  const float* bk = (const float*)d_in[4];
  const float* Wv = (const float*)d_in[5];
  const float* bv = (const float*)d_in[6];
  const float* Wo = (const float*)d_in[7];
  const float* bo = (const float*)d_in[8];

  char* w = (char*)d_ws;
  f16* xb  = (f16*)(w);                          // 8 MiB  : x in f16
  f16* wqt = (f16*)(w + ((size_t)8 << 20));      // 2 MiB  : Wq^T f16
  f16* wkt = (f16*)(w + ((size_t)10 << 20));     //        (wq/wk/wv contiguous)
  f16* wvt = (f16*)(w + ((size_t)12 << 20));
  f16* wot = (f16*)(w + ((size_t)14 << 20));
  f16* q   = (f16*)(w + ((size_t)16 << 20));     // 8 MiB  : Q [4096][1024]
  f16* kk  = (f16*)(w + ((size_t)24 << 20));     // 8 MiB  : K
  f16* vt  = (f16*)(w + ((size_t)32 << 20));     // 8 MiB  : V^T [b][h][d][t]
  f16* ao  = (f16*)(w + ((size_t)40 << 20));     // 8 MiB  : attn out

  prep_kernel<<<6144, 256, 0, stream>>>(x, xb, Wq, Wk, Wv, Wo,
                                        wqt, wkt, wvt, wot);
  gemm_qkv_kernel<<<768, 256, 0, stream>>>(xb, wqt, bq, bk, bv, q, kk, vt);
  attn_kernel<<<512, 256, 0, stream>>>(q, kk, vt, ao);
  gemm_o_kernel<<<512, 256, 0, stream>>>(ao, wot, bo, (float*)d_out);
}

// Round 11
// 76.966 us; speedup vs baseline: 1.1015x; 1.0224x over previous
//
#include <hip/hip_runtime.h>

// ---------------------------------------------------------------------------
// SlidingWindowAttention on MI355X (gfx950)
// B=2 T=2048 C=1024 H=16 D=64 WINDOW=256
// f16 16x16x32 MFMA. qkv: 128x128/4-wave 2-barrier core (at ceiling).
// attn v5: swapped QK^T, in-register P. gemm_o v3: 64x64 tiles, 4 blocks/CU.
// ---------------------------------------------------------------------------

typedef _Float16 f16;
typedef _Float16 half8 __attribute__((ext_vector_type(8)));
typedef _Float16 half4 __attribute__((ext_vector_type(4)));
typedef float    f32x4 __attribute__((ext_vector_type(4)));

#define MFMA16(a, b, c) __builtin_amdgcn_mfma_f32_16x16x32_f16((a), (b), (c), 0, 0, 0)

__device__ __forceinline__ void gload16(const void* g, void* l) {
  __builtin_amdgcn_global_load_lds(
      (const __attribute__((address_space(1))) void*)g,
      (__attribute__((address_space(3))) void*)l, 16, 0, 0);
}

// ---------------------------------------------------------------------------
// prep v2: blocks 0..2047 convert x f32->f16 (8 elems/thread);
// blocks 2048..4095 transpose weights in 64(k) x 32(n) tiles, all threads
// active in both phases (read: 2x float4/thread, write: 1x half8/thread).
__global__ __launch_bounds__(256) void prep_kernel(
    const float* __restrict__ x, f16* __restrict__ xb,
    const float* __restrict__ W0, const float* __restrict__ W1,
    const float* __restrict__ W2, const float* __restrict__ W3,
    f16* __restrict__ T0, f16* __restrict__ T1,
    f16* __restrict__ T2, f16* __restrict__ T3) {
  const int bid = blockIdx.x;
  if (bid < 2048) {
    const int idx = (bid * 256 + threadIdx.x) * 8;
    const float4 a = *(const float4*)(x + idx);
    const float4 b = *(const float4*)(x + idx + 4);
    half8 h;
    h[0] = (f16)a.x; h[1] = (f16)a.y; h[2] = (f16)a.z; h[3] = (f16)a.w;
    h[4] = (f16)b.x; h[5] = (f16)b.y; h[6] = (f16)b.z; h[7] = (f16)b.w;
    *(half8*)(xb + idx) = h;
    return;
  }
  __shared__ float tile[64][33];
  const int bid2 = bid - 2048;
  const int mat = bid2 >> 9;                // 512 tiles per matrix
  const int rem = bid2 & 511;
  const int kt = (rem >> 5) * 64;           // 16 k-tiles
  const int nt = (rem & 31) * 32;           // 32 n-tiles
  const float* W = mat == 0 ? W0 : mat == 1 ? W1 : mat == 2 ? W2 : W3;
  f16* T = mat == 0 ? T0 : mat == 1 ? T1 : mat == 2 ? T2 : T3;
  const int tid = threadIdx.x;
  const int r = tid >> 3;                   // 0..31
  const int c4 = (tid & 7) * 4;             // 0..28
  const float4 v0 = *(const float4*)(W + (size_t)(kt + r) * 1024 + nt + c4);
  const float4 v1 = *(const float4*)(W + (size_t)(kt + r + 32) * 1024 + nt + c4);
  tile[r][c4 + 0] = v0.x; tile[r][c4 + 1] = v0.y;
  tile[r][c4 + 2] = v0.z; tile[r][c4 + 3] = v0.w;
  tile[r + 32][c4 + 0] = v1.x; tile[r + 32][c4 + 1] = v1.y;
  tile[r + 32][c4 + 2] = v1.z; tile[r + 32][c4 + 3] = v1.w;
  __syncthreads();
  const int n = tid >> 3;                   // 0..31
  const int k8 = (tid & 7) * 8;             // 0..56
  half8 o;
  #pragma unroll
  for (int e = 0; e < 8; e++) o[e] = (f16)tile[k8 + e][n];
  *(half8*)(T + (size_t)(nt + n) * 1024 + kt + k8) = o;
}

// ---------------------------------------------------------------------------
// 4-wave 128x128 GEMM core: wave tile 64x64, BK=64, 16 K-steps.
__device__ __forceinline__ void gemm_core4(const f16* __restrict__ A,
                                           const f16* __restrict__ Bt,
                                           int m0, int n0,
                                           f16* As, f16* Bs,
                                           f32x4 acc[4][4]) {
  const int tid = threadIdx.x;
  const int lane = tid & 63, wave = tid >> 6;
  const int wm = wave >> 1, wn = wave & 1;
  const int fr = lane & 15, fg = lane >> 4;
  const int sx = (fr & 7) << 4;

  const int srow = wave * 32 + (lane >> 3);
  const int cc = lane & 7;
  const size_t go = (size_t)srow * 1024 + (size_t)((cc ^ (srow & 7)) * 8);
  const f16* ag = A + (size_t)m0 * 1024 + go;
  const f16* bg = Bt + (size_t)n0 * 1024 + go;
  f16* la = As + wave * 2048;
  f16* lb = Bs + wave * 2048;

  #pragma unroll
  for (int i = 0; i < 4; i++)
    #pragma unroll
    for (int j = 0; j < 4; j++) acc[i][j] = (f32x4){0.f, 0.f, 0.f, 0.f};

  for (int kt = 0; kt < 1024; kt += 64) {
    #pragma unroll
    for (int t = 0; t < 4; t++) {
      gload16(ag + kt + t * 8192, la + t * 512);
      gload16(bg + kt + t * 8192, lb + t * 512);
    }
    __syncthreads();
    const char* Ab = (const char*)As;
    const char* Bb = (const char*)Bs;
    #pragma unroll
    for (int kk = 0; kk < 2; kk++) {
      half8 af[4], bf[4];
      const int co = (kk * 64 + fg * 16) ^ sx;
      #pragma unroll
      for (int mf = 0; mf < 4; mf++)
        af[mf] = *(const half8*)(Ab + (wm * 64 + mf * 16 + fr) * 128 + co);
      #pragma unroll
      for (int nf = 0; nf < 4; nf++)
        bf[nf] = *(const half8*)(Bb + (wn * 64 + nf * 16 + fr) * 128 + co);
      #pragma unroll
      for (int mf = 0; mf < 4; mf++)
        #pragma unroll
        for (int nf = 0; nf < 4; nf++)
          acc[mf][nf] = MFMA16(af[mf], bf[nf], acc[mf][nf]);
    }
    __syncthreads();
  }
}

// ---------------------------------------------------------------------------
// Fused QKV: grid 768 = 32m x 24n, 256 threads, 3 blocks/CU.
__global__ __launch_bounds__(256, 3) void gemm_qkv_kernel(
    const f16* __restrict__ xb, const f16* __restrict__ wt,
    const float* __restrict__ bq, const float* __restrict__ bk,
    const float* __restrict__ bv,
    f16* __restrict__ qo, f16* __restrict__ ko, f16* __restrict__ vt) {
  __shared__ __align__(16) f16 As[128 * 64];
  __shared__ __align__(16) f16 Bs[128 * 64];
  const int wg = (blockIdx.x & 7) * 96 + (blockIdx.x >> 3);
  const int m0 = (wg & 31) * 128;
  const int n0 = (wg >> 5) * 128;
  f32x4 acc[4][4];
  gemm_core4(xb, wt, m0, n0, As, Bs, acc);

  const int lane = threadIdx.x & 63, wave = threadIdx.x >> 6;
  const int wm = wave >> 1, wn = wave & 1;
  const int fr = lane & 15, fg = lane >> 4;
  const int matid = n0 >> 10;
  const int nc0 = n0 & 1023;
  const float* bias = matid == 0 ? bq : matid == 1 ? bk : bv;
  if (matid < 2) {
    f16* out = matid == 0 ? qo : ko;
    #pragma unroll
    for (int mf = 0; mf < 4; mf++)
      #pragma unroll
      for (int nf = 0; nf < 4; nf++) {
        const int col = nc0 + wn * 64 + nf * 16 + fr;
        const float bb = bias[col];
        #pragma unroll
        for (int r = 0; r < 4; r++) {
          const int row = m0 + wm * 64 + mf * 16 + fg * 4 + r;
          out[(size_t)row * 1024 + col] = (f16)(acc[mf][nf][r] + bb);
        }
      }
  } else {
    #pragma unroll
    for (int mf = 0; mf < 4; mf++)
      #pragma unroll
      for (int nf = 0; nf < 4; nf++) {
        const int row = m0 + wm * 64 + mf * 16 + fg * 4;
        const int col = nc0 + wn * 64 + nf * 16 + fr;
        const int b = row >> 11, t = row & 2047;
        const int h = col >> 6, d = col & 63;
        const float bb = bias[col];
        half4 vv;
        #pragma unroll
        for (int r = 0; r < 4; r++) vv[r] = (f16)(acc[mf][nf][r] + bb);
        *(half4*)(vt + (((size_t)(b * 16 + h)) * 64 + d) * 2048 + t) = vv;
      }
  }
}

// ---------------------------------------------------------------------------
// Output projection v3: 64x64 tiles, grid 1024 = 64m x 16n -> 4 blocks/CU.
// 4 waves (2M x 2N), wave tile 32x32. TLP hides the 2-barrier drain.
__global__ __launch_bounds__(256, 4) void gemm_o_kernel(
    const f16* __restrict__ ao, const f16* __restrict__ wot,
    const float* __restrict__ bo, float* __restrict__ out) {
  __shared__ __align__(16) f16 As[64 * 64];
  __shared__ __align__(16) f16 Bs[64 * 64];
  const int wg = (blockIdx.x & 7) * 128 + (blockIdx.x >> 3);  // 1024 = 8*128
  const int m0 = (wg & 63) * 64;
  const int n0 = (wg >> 6) * 64;

  const int tid = threadIdx.x;
  const int lane = tid & 63, wave = tid >> 6;
  const int wm = wave >> 1, wn = wave & 1;
  const int fr = lane & 15, fg = lane >> 4;
  const int sx = (fr & 7) << 4;

  const int cc = lane & 7;
  const int srow = wave * 16 + (lane >> 3);        // rows 0..63 (t adds 8)
  const size_t go = (size_t)srow * 1024 + (size_t)((cc ^ (srow & 7)) * 8);
  const f16* ag = ao + (size_t)m0 * 1024 + go;
  const f16* bg = wot + (size_t)n0 * 1024 + go;
  f16* la = As + wave * 1024;
  f16* lb = Bs + wave * 1024;

  f32x4 acc[2][2];
  #pragma unroll
  for (int i = 0; i < 2; i++)
    #pragma unroll
    for (int j = 0; j < 2; j++) acc[i][j] = (f32x4){0.f, 0.f, 0.f, 0.f};

  for (int kt = 0; kt < 1024; kt += 64) {
    #pragma unroll
    for (int t = 0; t < 2; t++) {
      gload16(ag + kt + t * 8192, la + t * 512);
      gload16(bg + kt + t * 8192, lb + t * 512);
    }
    __syncthreads();
    const char* Ab = (const char*)As;
    const char* Bb = (const char*)Bs;
    #pragma unroll
    for (int kk = 0; kk < 2; kk++) {
      half8 af[2], bf[2];
      const int co = (kk * 64 + fg * 16) ^ sx;
      #pragma unroll
      for (int mf = 0; mf < 2; mf++)
        af[mf] = *(const half8*)(Ab + (wm * 32 + mf * 16 + fr) * 128 + co);
      #pragma unroll
      for (int nf = 0; nf < 2; nf++)
        bf[nf] = *(const half8*)(Bb + (wn * 32 + nf * 16 + fr) * 128 + co);
      #pragma unroll
      for (int mf = 0; mf < 2; mf++)
        #pragma unroll
        for (int nf = 0; nf < 2; nf++)
          acc[mf][nf] = MFMA16(af[mf], bf[nf], acc[mf][nf]);
    }
    __syncthreads();
  }

  #pragma unroll
  for (int mf = 0; mf < 2; mf++)
    #pragma unroll
    for (int nf = 0; nf < 2; nf++) {
      const int col = n0 + wn * 32 + nf * 16 + fr;
      const float bb = bo[col];
      #pragma unroll
      for (int r = 0; r < 4; r++) {
        const int row = m0 + wm * 32 + mf * 16 + fg * 4 + r;
        out[(size_t)row * 1024 + col] = acc[mf][nf][r] + bb;
      }
    }
}

// ---------------------------------------------------------------------------
// Sliding-window attention v5: QBLK=128, KVBLK=64, XCD-clustered bh.
// Swapped QK^T -> P assembled in registers; PV in permuted key order.
__global__ __launch_bounds__(256, 3) void attn_kernel(
    const f16* __restrict__ Q, const f16* __restrict__ K,
    const f16* __restrict__ Vt, f16* __restrict__ Ao) {
  __shared__ __align__(16) f16 Ks[2][64 * 64];
  __shared__ __align__(16) f16 Vs[2][64 * 64];

  const int tid = threadIdx.x, lane = tid & 63, wave = tid >> 6;
  const int fr = lane & 15, g = lane >> 4;
  const int wg = (blockIdx.x & 7) * 64 + (blockIdx.x >> 3);
  const int qt = wg & 15, bh = wg >> 4;
  const int b = bh >> 4, h = bh & 15;
  const int q0 = qt * 128;
  const int qr = q0 + wave * 32;

  const f16* Qb = Q + ((size_t)(b * 2048 + qr)) * 1024 + h * 64;
  half8 qf[2][2];
  #pragma unroll
  for (int mc = 0; mc < 2; mc++)
    #pragma unroll
    for (int kk = 0; kk < 2; kk++)
      qf[mc][kk] =
          *(const half8*)(Qb + (size_t)(mc * 16 + fr) * 1024 + kk * 32 + g * 8);

  const char* Kg = (const char*)(K + ((size_t)(b * 2048)) * 1024 + h * 64);
  const char* Vg = (const char*)(Vt + ((size_t)(b * 16 + h)) * 64 * 2048);

  const int sr = wave * 16 + (lane >> 3);
  const int sco = ((lane & 7) ^ (sr & 7)) << 4;

  auto stageKV = [&](int buf, int jt) {
    #pragma unroll
    for (int t = 0; t < 2; t++) {
      gload16(Kg + (size_t)(jt + sr + t * 8) * 2048 + sco,
              (f16*)Ks[buf] + wave * 1024 + t * 512);
      gload16(Vg + (size_t)(sr + t * 8) * 4096 + (size_t)jt * 2 + sco,
              (f16*)Vs[buf] + wave * 1024 + t * 512);
    }
  };

  const int t0 = q0 >= 256 ? (q0 - 256) >> 6 : 0;
  const int t1 = (q0 + 127) >> 6;

  f32x4 O[2][4];
  #pragma unroll
  for (int mc = 0; mc < 2; mc++)
    #pragma unroll
    for (int nt = 0; nt < 4; nt++) O[mc][nt] = (f32x4){0.f, 0.f, 0.f, 0.f};
  float lsum[2] = {0.f, 0.f};

  stageKV(0, t0 * 64);
  __syncthreads();

  for (int tt = t0; tt <= t1; ++tt) {
    const int cur = (tt - t0) & 1;
    if (tt < t1) stageKV(cur ^ 1, (tt + 1) * 64);
    const int jt = tt * 64;
    const bool alive = (jt <= qr + 31) && (jt + 63 >= qr - 256);
    if (alive) {
      const char* Kb = (const char*)Ks[cur];
      const char* Vb = (const char*)Vs[cur];
      half8 pa[2][2];
      #pragma unroll
      for (int jj = 0; jj < 4; ++jj) {
        const int kj = jj * 16 + fr;
        const char* krow = Kb + kj * 128;
        const int kswz = (kj & 7) << 4;
        const half8 kf0 = *(const half8*)(krow + ((g * 16) ^ kswz));
        const half8 kf1 = *(const half8*)(krow + ((64 + g * 16) ^ kswz));
        #pragma unroll
        for (int mc = 0; mc < 2; ++mc) {
          f32x4 z = (f32x4){0.f, 0.f, 0.f, 0.f};
          z = MFMA16(kf0, qf[mc][0], z);
          z = MFMA16(kf1, qf[mc][1], z);
          const int eb = qr + mc * 16 + fr - jt - jj * 16 - g * 4;
          #pragma unroll
          for (int r = 0; r < 4; ++r) {
            const float a = __expf(z[r] * 0.125f - 3.0f);
            const float p = ((unsigned)(eb - r) <= 256u) ? a : 0.f;
            lsum[mc] += p;
            pa[mc][jj >> 1][(jj & 1) * 4 + r] = (f16)p;
          }
        }
      }
      #pragma unroll
      for (int ks = 0; ks < 2; ++ks) {
        #pragma unroll
        for (int nt = 0; nt < 4; ++nt) {
          const int vd = nt * 16 + fr;
          const int sw = (vd & 7) << 4;
          const half4 vlo =
              *(const half4*)(Vb + vd * 128 + ((ks * 64 + 8 * g) ^ sw));
          const half4 vhi =
              *(const half4*)(Vb + vd * 128 + ((ks * 64 + 32 + 8 * g) ^ sw));
          half8 vf;
          vf[0] = vlo[0]; vf[1] = vlo[1]; vf[2] = vlo[2]; vf[3] = vlo[3];
          vf[4] = vhi[0]; vf[5] = vhi[1]; vf[6] = vhi[2]; vf[7] = vhi[3];
          O[0][nt] = MFMA16(pa[0][ks], vf, O[0][nt]);
          O[1][nt] = MFMA16(pa[1][ks], vf, O[1][nt]);
        }
      }
    }
    __syncthreads();
  }

  float inv[2][4];
  #pragma unroll
  for (int mc = 0; mc < 2; ++mc) {
    float t = lsum[mc];
    t += __shfl_xor(t, 16);
    t += __shfl_xor(t, 32);
    #pragma unroll
    for (int r = 0; r < 4; ++r) inv[mc][r] = 1.0f / __shfl(t, g * 4 + r);
  }
  f16* Aout = Ao + ((size_t)(b * 2048 + qr)) * 1024 + h * 64;
  #pragma unroll
  for (int mc = 0; mc < 2; ++mc)
    #pragma unroll
    for (int nt = 0; nt < 4; ++nt)
      #pragma unroll
      for (int r = 0; r < 4; ++r)
        Aout[(size_t)(mc * 16 + g * 4 + r) * 1024 + nt * 16 + fr] =
            (f16)(O[mc][nt][r] * inv[mc][r]);
}

// ---------------------------------------------------------------------------
extern "C" void kernel_launch(void* const* d_in, const int* in_sizes, int n_in,
                              void* d_out, int out_size, void* d_ws,
                              size_t ws_size, hipStream_t stream) {
  const float* x  = (const float*)d_in[0];
  const float* Wq = (const float*)d_in[1];
  const float* bq = (const float*)d_in[2];
  const float* Wk = (const float*)d_in[3];
  const float* bk = (const float*)d_in[4];
  const float* Wv = (const float*)d_in[5];
  const float* bv = (const float*)d_in[6];
  const float* Wo = (const float*)d_in[7];
  const float* bo = (const float*)d_in[8];

  char* w = (char*)d_ws;
  f16* xb  = (f16*)(w);                          // 8 MiB  : x in f16
  f16* wqt = (f16*)(w + ((size_t)8 << 20));      // 2 MiB  : Wq^T f16
  f16* wkt = (f16*)(w + ((size_t)10 << 20));     //        (wq/wk/wv contiguous)
  f16* wvt = (f16*)(w + ((size_t)12 << 20));
  f16* wot = (f16*)(w + ((size_t)14 << 20));
  f16* q   = (f16*)(w + ((size_t)16 << 20));     // 8 MiB  : Q [4096][1024]
  f16* kk  = (f16*)(w + ((size_t)24 << 20));     // 8 MiB  : K
  f16* vt  = (f16*)(w + ((size_t)32 << 20));     // 8 MiB  : V^T [b][h][d][t]
  f16* ao  = (f16*)(w + ((size_t)40 << 20));     // 8 MiB  : attn out

  prep_kernel<<<4096, 256, 0, stream>>>(x, xb, Wq, Wk, Wv, Wo,
                                        wqt, wkt, wvt, wot);
  gemm_qkv_kernel<<<768, 256, 0, stream>>>(xb, wqt, bq, bk, bv, q, kk, vt);
  attn_kernel<<<512, 256, 0, stream>>>(q, kk, vt, ao);
  gemm_o_kernel<<<1024, 256, 0, stream>>>(ao, wot, bo, (float*)d_out);
}

// Round 12
// 74.198 us; speedup vs baseline: 1.1426x; 1.0373x over previous
//
#include <hip/hip_runtime.h>

// ---------------------------------------------------------------------------
// SlidingWindowAttention on MI355X (gfx950)
// B=2 T=2048 C=1024 H=16 D=64 WINDOW=256
// f16 16x16x32 MFMA. qkv: 128x128/4-wave 2-barrier core; gemm_o: 64x64 tiles,
// 4 blocks/CU; attn v5: swapped QK^T, in-register P.
// This round: 2-D XCD tile partition so each XCD's staging set fits L2
// (qkv: 4x2 regions -> 5 MB/XCD; gemm_o: 4x2 -> 3 MB/XCD < 4 MB L2).
// ---------------------------------------------------------------------------

typedef _Float16 f16;
typedef _Float16 half8 __attribute__((ext_vector_type(8)));
typedef _Float16 half4 __attribute__((ext_vector_type(4)));
typedef float    f32x4 __attribute__((ext_vector_type(4)));

#define MFMA16(a, b, c) __builtin_amdgcn_mfma_f32_16x16x32_f16((a), (b), (c), 0, 0, 0)

__device__ __forceinline__ void gload16(const void* g, void* l) {
  __builtin_amdgcn_global_load_lds(
      (const __attribute__((address_space(1))) void*)g,
      (__attribute__((address_space(3))) void*)l, 16, 0, 0);
}

// ---------------------------------------------------------------------------
// prep v2: blocks 0..2047 convert x f32->f16 (8 elems/thread);
// blocks 2048..4095 transpose weights in 64(k) x 32(n) tiles.
__global__ __launch_bounds__(256) void prep_kernel(
    const float* __restrict__ x, f16* __restrict__ xb,
    const float* __restrict__ W0, const float* __restrict__ W1,
    const float* __restrict__ W2, const float* __restrict__ W3,
    f16* __restrict__ T0, f16* __restrict__ T1,
    f16* __restrict__ T2, f16* __restrict__ T3) {
  const int bid = blockIdx.x;
  if (bid < 2048) {
    const int idx = (bid * 256 + threadIdx.x) * 8;
    const float4 a = *(const float4*)(x + idx);
    const float4 b = *(const float4*)(x + idx + 4);
    half8 h;
    h[0] = (f16)a.x; h[1] = (f16)a.y; h[2] = (f16)a.z; h[3] = (f16)a.w;
    h[4] = (f16)b.x; h[5] = (f16)b.y; h[6] = (f16)b.z; h[7] = (f16)b.w;
    *(half8*)(xb + idx) = h;
    return;
  }
  __shared__ float tile[64][33];
  const int bid2 = bid - 2048;
  const int mat = bid2 >> 9;
  const int rem = bid2 & 511;
  const int kt = (rem >> 5) * 64;
  const int nt = (rem & 31) * 32;
  const float* W = mat == 0 ? W0 : mat == 1 ? W1 : mat == 2 ? W2 : W3;
  f16* T = mat == 0 ? T0 : mat == 1 ? T1 : mat == 2 ? T2 : T3;
  const int tid = threadIdx.x;
  const int r = tid >> 3;
  const int c4 = (tid & 7) * 4;
  const float4 v0 = *(const float4*)(W + (size_t)(kt + r) * 1024 + nt + c4);
  const float4 v1 = *(const float4*)(W + (size_t)(kt + r + 32) * 1024 + nt + c4);
  tile[r][c4 + 0] = v0.x; tile[r][c4 + 1] = v0.y;
  tile[r][c4 + 2] = v0.z; tile[r][c4 + 3] = v0.w;
  tile[r + 32][c4 + 0] = v1.x; tile[r + 32][c4 + 1] = v1.y;
  tile[r + 32][c4 + 2] = v1.z; tile[r + 32][c4 + 3] = v1.w;
  __syncthreads();
  const int n = tid >> 3;
  const int k8 = (tid & 7) * 8;
  half8 o;
  #pragma unroll
  for (int e = 0; e < 8; e++) o[e] = (f16)tile[k8 + e][n];
  *(half8*)(T + (size_t)(nt + n) * 1024 + kt + k8) = o;
}

// ---------------------------------------------------------------------------
// 4-wave 128x128 GEMM core: wave tile 64x64, BK=64, 16 K-steps.
__device__ __forceinline__ void gemm_core4(const f16* __restrict__ A,
                                           const f16* __restrict__ Bt,
                                           int m0, int n0,
                                           f16* As, f16* Bs,
                                           f32x4 acc[4][4]) {
  const int tid = threadIdx.x;
  const int lane = tid & 63, wave = tid >> 6;
  const int wm = wave >> 1, wn = wave & 1;
  const int fr = lane & 15, fg = lane >> 4;
  const int sx = (fr & 7) << 4;

  const int srow = wave * 32 + (lane >> 3);
  const int cc = lane & 7;
  const size_t go = (size_t)srow * 1024 + (size_t)((cc ^ (srow & 7)) * 8);
  const f16* ag = A + (size_t)m0 * 1024 + go;
  const f16* bg = Bt + (size_t)n0 * 1024 + go;
  f16* la = As + wave * 2048;
  f16* lb = Bs + wave * 2048;

  #pragma unroll
  for (int i = 0; i < 4; i++)
    #pragma unroll
    for (int j = 0; j < 4; j++) acc[i][j] = (f32x4){0.f, 0.f, 0.f, 0.f};

  for (int kt = 0; kt < 1024; kt += 64) {
    #pragma unroll
    for (int t = 0; t < 4; t++) {
      gload16(ag + kt + t * 8192, la + t * 512);
      gload16(bg + kt + t * 8192, lb + t * 512);
    }
    __syncthreads();
    const char* Ab = (const char*)As;
    const char* Bb = (const char*)Bs;
    #pragma unroll
    for (int kk = 0; kk < 2; kk++) {
      half8 af[4], bf[4];
      const int co = (kk * 64 + fg * 16) ^ sx;
      #pragma unroll
      for (int mf = 0; mf < 4; mf++)
        af[mf] = *(const half8*)(Ab + (wm * 64 + mf * 16 + fr) * 128 + co);
      #pragma unroll
      for (int nf = 0; nf < 4; nf++)
        bf[nf] = *(const half8*)(Bb + (wn * 64 + nf * 16 + fr) * 128 + co);
      #pragma unroll
      for (int mf = 0; mf < 4; mf++)
        #pragma unroll
        for (int nf = 0; nf < 4; nf++)
          acc[mf][nf] = MFMA16(af[mf], bf[nf], acc[mf][nf]);
    }
    __syncthreads();
  }
}

// ---------------------------------------------------------------------------
// Fused QKV: grid 768, 256 threads, 3 blocks/CU.
// 2-D XCD partition: 8 XCDs as 4(m) x 2(n) regions of 8 m-tiles x 12 n-tiles
// -> per-XCD staging set 2 MB A + 3 MB B (was 8.75 MB, >> 4 MB L2).
__global__ __launch_bounds__(256, 3) void gemm_qkv_kernel(
    const f16* __restrict__ xb, const f16* __restrict__ wt,
    const float* __restrict__ bq, const float* __restrict__ bk,
    const float* __restrict__ bv,
    f16* __restrict__ qo, f16* __restrict__ ko, f16* __restrict__ vt) {
  __shared__ __align__(16) f16 As[128 * 64];
  __shared__ __align__(16) f16 Bs[128 * 64];
  const int xcd = blockIdx.x & 7;
  const int rr = blockIdx.x >> 3;                  // 0..95
  const int m0 = (((xcd & 3) * 8) + (rr & 7)) * 128;
  const int n0 = (((xcd >> 2) * 12) + (rr >> 3)) * 128;
  f32x4 acc[4][4];
  gemm_core4(xb, wt, m0, n0, As, Bs, acc);

  const int lane = threadIdx.x & 63, wave = threadIdx.x >> 6;
  const int wm = wave >> 1, wn = wave & 1;
  const int fr = lane & 15, fg = lane >> 4;
  const int matid = n0 >> 10;
  const int nc0 = n0 & 1023;
  const float* bias = matid == 0 ? bq : matid == 1 ? bk : bv;
  if (matid < 2) {
    f16* out = matid == 0 ? qo : ko;
    #pragma unroll
    for (int mf = 0; mf < 4; mf++)
      #pragma unroll
      for (int nf = 0; nf < 4; nf++) {
        const int col = nc0 + wn * 64 + nf * 16 + fr;
        const float bb = bias[col];
        #pragma unroll
        for (int r = 0; r < 4; r++) {
          const int row = m0 + wm * 64 + mf * 16 + fg * 4 + r;
          out[(size_t)row * 1024 + col] = (f16)(acc[mf][nf][r] + bb);
        }
      }
  } else {
    #pragma unroll
    for (int mf = 0; mf < 4; mf++)
      #pragma unroll
      for (int nf = 0; nf < 4; nf++) {
        const int row = m0 + wm * 64 + mf * 16 + fg * 4;
        const int col = nc0 + wn * 64 + nf * 16 + fr;
        const int b = row >> 11, t = row & 2047;
        const int h = col >> 6, d = col & 63;
        const float bb = bias[col];
        half4 vv;
        #pragma unroll
        for (int r = 0; r < 4; r++) vv[r] = (f16)(acc[mf][nf][r] + bb);
        *(half4*)(vt + (((size_t)(b * 16 + h)) * 64 + d) * 2048 + t) = vv;
      }
  }
}

// ---------------------------------------------------------------------------
// Output projection v3: 64x64 tiles, grid 1024, 4 blocks/CU.
// 2-D XCD partition: 4(m) x 2(n) regions of 16 x 8 tiles -> 3 MB/XCD < L2.
__global__ __launch_bounds__(256, 4) void gemm_o_kernel(
    const f16* __restrict__ ao, const f16* __restrict__ wot,
    const float* __restrict__ bo, float* __restrict__ out) {
  __shared__ __align__(16) f16 As[64 * 64];
  __shared__ __align__(16) f16 Bs[64 * 64];
  const int xcd = blockIdx.x & 7;
  const int rr = blockIdx.x >> 3;                  // 0..127
  const int m0 = (((xcd & 3) * 16) + (rr & 15)) * 64;
  const int n0 = (((xcd >> 2) * 8) + (rr >> 4)) * 64;

  const int tid = threadIdx.x;
  const int lane = tid & 63, wave = tid >> 6;
  const int wm = wave >> 1, wn = wave & 1;
  const int fr = lane & 15, fg = lane >> 4;
  const int sx = (fr & 7) << 4;

  const int cc = lane & 7;
  const int srow = wave * 16 + (lane >> 3);
  const size_t go = (size_t)srow * 1024 + (size_t)((cc ^ (srow & 7)) * 8);
  const f16* ag = ao + (size_t)m0 * 1024 + go;
  const f16* bg = wot + (size_t)n0 * 1024 + go;
  f16* la = As + wave * 1024;
  f16* lb = Bs + wave * 1024;

  f32x4 acc[2][2];
  #pragma unroll
  for (int i = 0; i < 2; i++)
    #pragma unroll
    for (int j = 0; j < 2; j++) acc[i][j] = (f32x4){0.f, 0.f, 0.f, 0.f};

  for (int kt = 0; kt < 1024; kt += 64) {
    #pragma unroll
    for (int t = 0; t < 2; t++) {
      gload16(ag + kt + t * 8192, la + t * 512);
      gload16(bg + kt + t * 8192, lb + t * 512);
    }
    __syncthreads();
    const char* Ab = (const char*)As;
    const char* Bb = (const char*)Bs;
    #pragma unroll
    for (int kk = 0; kk < 2; kk++) {
      half8 af[2], bf[2];
      const int co = (kk * 64 + fg * 16) ^ sx;
      #pragma unroll
      for (int mf = 0; mf < 2; mf++)
        af[mf] = *(const half8*)(Ab + (wm * 32 + mf * 16 + fr) * 128 + co);
      #pragma unroll
      for (int nf = 0; nf < 2; nf++)
        bf[nf] = *(const half8*)(Bb + (wn * 32 + nf * 16 + fr) * 128 + co);
      #pragma unroll
      for (int mf = 0; mf < 2; mf++)
        #pragma unroll
        for (int nf = 0; nf < 2; nf++)
          acc[mf][nf] = MFMA16(af[mf], bf[nf], acc[mf][nf]);
    }
    __syncthreads();
  }

  #pragma unroll
  for (int mf = 0; mf < 2; mf++)
    #pragma unroll
    for (int nf = 0; nf < 2; nf++) {
      const int col = n0 + wn * 32 + nf * 16 + fr;
      const float bb = bo[col];
      #pragma unroll
      for (int r = 0; r < 4; r++) {
        const int row = m0 + wm * 32 + mf * 16 + fg * 4 + r;
        out[(size_t)row * 1024 + col] = acc[mf][nf][r] + bb;
      }
    }
}

// ---------------------------------------------------------------------------
// Sliding-window attention v5: QBLK=128, KVBLK=64, XCD-clustered bh.
// Swapped QK^T -> P assembled in registers; PV in permuted key order.
__global__ __launch_bounds__(256, 3) void attn_kernel(
    const f16* __restrict__ Q, const f16* __restrict__ K,
    const f16* __restrict__ Vt, f16* __restrict__ Ao) {
  __shared__ __align__(16) f16 Ks[2][64 * 64];
  __shared__ __align__(16) f16 Vs[2][64 * 64];

  const int tid = threadIdx.x, lane = tid & 63, wave = tid >> 6;
  const int fr = lane & 15, g = lane >> 4;
  const int wg = (blockIdx.x & 7) * 64 + (blockIdx.x >> 3);
  const int qt = wg & 15, bh = wg >> 4;
  const int b = bh >> 4, h = bh & 15;
  const int q0 = qt * 128;
  const int qr = q0 + wave * 32;

  const f16* Qb = Q + ((size_t)(b * 2048 + qr)) * 1024 + h * 64;
  half8 qf[2][2];
  #pragma unroll
  for (int mc = 0; mc < 2; mc++)
    #pragma unroll
    for (int kk = 0; kk < 2; kk++)
      qf[mc][kk] =
          *(const half8*)(Qb + (size_t)(mc * 16 + fr) * 1024 + kk * 32 + g * 8);

  const char* Kg = (const char*)(K + ((size_t)(b * 2048)) * 1024 + h * 64);
  const char* Vg = (const char*)(Vt + ((size_t)(b * 16 + h)) * 64 * 2048);

  const int sr = wave * 16 + (lane >> 3);
  const int sco = ((lane & 7) ^ (sr & 7)) << 4;

  auto stageKV = [&](int buf, int jt) {
    #pragma unroll
    for (int t = 0; t < 2; t++) {
      gload16(Kg + (size_t)(jt + sr + t * 8) * 2048 + sco,
              (f16*)Ks[buf] + wave * 1024 + t * 512);
      gload16(Vg + (size_t)(sr + t * 8) * 4096 + (size_t)jt * 2 + sco,
              (f16*)Vs[buf] + wave * 1024 + t * 512);
    }
  };

  const int t0 = q0 >= 256 ? (q0 - 256) >> 6 : 0;
  const int t1 = (q0 + 127) >> 6;

  f32x4 O[2][4];
  #pragma unroll
  for (int mc = 0; mc < 2; mc++)
    #pragma unroll
    for (int nt = 0; nt < 4; nt++) O[mc][nt] = (f32x4){0.f, 0.f, 0.f, 0.f};
  float lsum[2] = {0.f, 0.f};

  stageKV(0, t0 * 64);
  __syncthreads();

  for (int tt = t0; tt <= t1; ++tt) {
    const int cur = (tt - t0) & 1;
    if (tt < t1) stageKV(cur ^ 1, (tt + 1) * 64);
    const int jt = tt * 64;
    const bool alive = (jt <= qr + 31) && (jt + 63 >= qr - 256);
    if (alive) {
      const char* Kb = (const char*)Ks[cur];
      const char* Vb = (const char*)Vs[cur];
      half8 pa[2][2];
      #pragma unroll
      for (int jj = 0; jj < 4; ++jj) {
        const int kj = jj * 16 + fr;
        const char* krow = Kb + kj * 128;
        const int kswz = (kj & 7) << 4;
        const half8 kf0 = *(const half8*)(krow + ((g * 16) ^ kswz));
        const half8 kf1 = *(const half8*)(krow + ((64 + g * 16) ^ kswz));
        #pragma unroll
        for (int mc = 0; mc < 2; ++mc) {
          f32x4 z = (f32x4){0.f, 0.f, 0.f, 0.f};
          z = MFMA16(kf0, qf[mc][0], z);
          z = MFMA16(kf1, qf[mc][1], z);
          const int eb = qr + mc * 16 + fr - jt - jj * 16 - g * 4;
          #pragma unroll
          for (int r = 0; r < 4; ++r) {
            const float a = __expf(z[r] * 0.125f - 3.0f);
            const float p = ((unsigned)(eb - r) <= 256u) ? a : 0.f;
            lsum[mc] += p;
            pa[mc][jj >> 1][(jj & 1) * 4 + r] = (f16)p;
          }
        }
      }
      #pragma unroll
      for (int ks = 0; ks < 2; ++ks) {
        #pragma unroll
        for (int nt = 0; nt < 4; ++nt) {
          const int vd = nt * 16 + fr;
          const int sw = (vd & 7) << 4;
          const half4 vlo =
              *(const half4*)(Vb + vd * 128 + ((ks * 64 + 8 * g) ^ sw));
          const half4 vhi =
              *(const half4*)(Vb + vd * 128 + ((ks * 64 + 32 + 8 * g) ^ sw));
          half8 vf;
          vf[0] = vlo[0]; vf[1] = vlo[1]; vf[2] = vlo[2]; vf[3] = vlo[3];
          vf[4] = vhi[0]; vf[5] = vhi[1]; vf[6] = vhi[2]; vf[7] = vhi[3];
          O[0][nt] = MFMA16(pa[0][ks], vf, O[0][nt]);
          O[1][nt] = MFMA16(pa[1][ks], vf, O[1][nt]);
        }
      }
    }
    __syncthreads();
  }

  float inv[2][4];
  #pragma unroll
  for (int mc = 0; mc < 2; ++mc) {
    float t = lsum[mc];
    t += __shfl_xor(t, 16);
    t += __shfl_xor(t, 32);
    #pragma unroll
    for (int r = 0; r < 4; ++r) inv[mc][r] = 1.0f / __shfl(t, g * 4 + r);
  }
  f16* Aout = Ao + ((size_t)(b * 2048 + qr)) * 1024 + h * 64;
  #pragma unroll
  for (int mc = 0; mc < 2; ++mc)
    #pragma unroll
    for (int nt = 0; nt < 4; ++nt)
      #pragma unroll
      for (int r = 0; r < 4; ++r)
        Aout[(size_t)(mc * 16 + g * 4 + r) * 1024 + nt * 16 + fr] =
            (f16)(O[mc][nt][r] * inv[mc][r]);
}

// ---------------------------------------------------------------------------
extern "C" void kernel_launch(void* const* d_in, const int* in_sizes, int n_in,
                              void* d_out, int out_size, void* d_ws,
                              size_t ws_size, hipStream_t stream) {
  const float* x  = (const float*)d_in[0];
  const float* Wq = (const float*)d_in[1];
  const float* bq = (const float*)d_in[2];
  const float* Wk = (const float*)d_in[3];
  const float* bk = (const float*)d_in[4];
  const float* Wv = (const float*)d_in[5];
  const float* bv = (const float*)d_in[6];
  const float* Wo = (const float*)d_in[7];
  const float* bo = (const float*)d_in[8];

  char* w = (char*)d_ws;
  f16* xb  = (f16*)(w);                          // 8 MiB  : x in f16
  f16* wqt = (f16*)(w + ((size_t)8 << 20));      // 2 MiB  : Wq^T f16
  f16* wkt = (f16*)(w + ((size_t)10 << 20));     //        (wq/wk/wv contiguous)
  f16* wvt = (f16*)(w + ((size_t)12 << 20));
  f16* wot = (f16*)(w + ((size_t)14 << 20));
  f16* q   = (f16*)(w + ((size_t)16 << 20));     // 8 MiB  : Q [4096][1024]
  f16* kk  = (f16*)(w + ((size_t)24 << 20));     // 8 MiB  : K
  f16* vt  = (f16*)(w + ((size_t)32 << 20));     // 8 MiB  : V^T [b][h][d][t]
  f16* ao  = (f16*)(w + ((size_t)40 << 20));     // 8 MiB  : attn out

  prep_kernel<<<4096, 256, 0, stream>>>(x, xb, Wq, Wk, Wv, Wo,
                                        wqt, wkt, wvt, wot);
  gemm_qkv_kernel<<<768, 256, 0, stream>>>(xb, wqt, bq, bk, bv, q, kk, vt);
  attn_kernel<<<512, 256, 0, stream>>>(q, kk, vt, ao);
  gemm_o_kernel<<<1024, 256, 0, stream>>>(ao, wot, bo, (float*)d_out);
}